// Round 13
// baseline (39937.189 us; speedup 1.0000x reference)
//
#include <hip/hip_runtime.h>
#include <hip/hip_bf16.h>
#include <math.h>

typedef __attribute__((ext_vector_type(8))) short bfrag8;   // 8 x bf16
typedef __attribute__((ext_vector_type(4))) float f32x4;    // MFMA accumulator
#define AGENT __HIP_MEMORY_SCOPE_AGENT

static __device__ __forceinline__ float b2f(unsigned short u) {
  union { unsigned int i; float f; } v; v.i = ((unsigned int)u) << 16; return v.f;
}
static __device__ __forceinline__ unsigned short f2b(float f) {
  union { float f; unsigned int i; } v; v.f = f;
  unsigned int i = v.i;
  return (unsigned short)((i + 0x7FFFu + ((i >> 16) & 1u)) >> 16);
}
static __device__ __forceinline__ float sigf(float x) { return 1.f / (1.f + __expf(-x)); }

// ---------------- workspace layout (bytes) ----------------
// cnt    [0,1024)        barrier lines (8 x 64B used) + cnt[255] = watchdog
// scan   [4096,102400)   cvec/coef/inv2
// pe     [102400,153600)
// h1     [153600,284672) 2 slots x 32x1024 bf16
// h2     [284672,415744)
// cst    [415744,677888) c1,c2 save (64 WG x 32 x 16 fp32 each)
// melpre @ 720896        (4,096,000)
// wbf    @ 4,849,664     (10,485,760)  Wih1 bf16 [4096][1280]
// wimg   @ 15,728,640    (25,165,824)  per-WG B-frag images: [64][3][4][32][64][8]
// inp1c  @ 41,943,040    ((TC+2) x 81920)

// ---------------- init ----------------
__global__ void k_init(unsigned int* hzero, unsigned int* cnt, float* pe) {
  int idx = blockIdx.x * 256 + threadIdx.x;
  if (idx < 256) cnt[idx] = 0u;
  if (idx < 65536) hzero[idx] = 0u;                     // h1+h2 both slots
  if (idx < 6400) {
    int p = idx >> 6, i = idx & 63;
    float freq = __expf(-(float)(2 * i) * 0.0719557842162201f); // ln(10000)/128
    float a = (float)p * freq;
    pe[p * 128 + 2 * i]     = sinf(a);
    pe[p * 128 + 2 * i + 1] = cosf(a);
  }
}

// ---------------- prenet -> inp1c[:, 0:256] ----------------
__global__ __launch_bounds__(256) void k_prenet(const float* __restrict__ din,
                                                const float* __restrict__ u1,
                                                const float* __restrict__ u2,
                                                const float* __restrict__ Wp1,
                                                const float* __restrict__ Wp2,
                                                unsigned short* inp1c, int t0, int tbeg) {
  __shared__ float dec[2560];
  __shared__ float X1[8192];
  int t = tbeg + blockIdx.x, tid = threadIdx.x;
  int tt = t - t0;
  for (int i = tid; i < 2560; i += 256) {
    int b = i / 80, f = i % 80;
    dec[i] = (t == 0) ? 0.f : din[((size_t)b * 80 + f) * 800 + (t - 1)];
  }
  __syncthreads();
  int n = tid;
  for (int b = 0; b < 32; ++b) {
    float s = 0.f;
    const float* w = Wp1 + n * 80;
    const float* d = dec + b * 80;
#pragma unroll 8
    for (int f = 0; f < 80; ++f) s += d[f] * w[f];
    s = fmaxf(s, 0.f);
    float m = (u1[((size_t)t * 32 + b) * 256 + n] >= 0.5f) ? 2.f : 0.f;
    X1[b * 256 + n] = s * m;
  }
  __syncthreads();
  for (int b = 0; b < 32; ++b) {
    float s = 0.f;
    const float* w = Wp2 + n * 256;
    const float* x = X1 + b * 256;
#pragma unroll 8
    for (int kk = 0; kk < 256; ++kk) s += x[kk] * w[kk];
    s = fmaxf(s, 0.f);
    float m = (u2[((size_t)t * 32 + b) * 256 + n] >= 0.5f) ? 2.f : 0.f;
    inp1c[((size_t)tt * 32 + b) * 1280 + n] = f2b(s * m);
  }
}

// ---------------- attention precompute ----------------
__global__ __launch_bounds__(256) void k_attn_prep(const float* __restrict__ dur,
                                                   const float* __restrict__ range,
                                                   float* cvec, float* coef, float* inv2) {
  __shared__ float s[256];
  int b = blockIdx.x, e = threadIdx.x;
  float d = dur[b * 256 + e];
  s[e] = d;
  __syncthreads();
  for (int off = 1; off < 256; off <<= 1) {
    float v = (e >= off) ? s[e - off] : 0.f;
    __syncthreads();
    s[e] = s[e] + v;
    __syncthreads();
  }
  float c = s[e] - 0.5f * d;
  float sg = range[b * 256 + e] + 1e-5f;
  cvec[b * 256 + e] = c;
  coef[b * 256 + e] = rsqrtf(6.283185307179586f * sg * sg);
  inv2[b * 256 + e] = 1.f / (2.f * sg * sg);
}

// ---------------- alignments output (fp32) ----------------
__global__ __launch_bounds__(256) void k_attn(const float* __restrict__ cvec,
                                              const float* __restrict__ coef,
                                              const float* __restrict__ inv2,
                                              float* out_align) {
  __shared__ float red[4];
  int t = blockIdx.x, b = blockIdx.y, e = threadIdx.x;
  float dt = (float)t - cvec[b * 256 + e];
  float p = coef[b * 256 + e] * __expf(-dt * dt * inv2[b * 256 + e]) + 1e-5f;
  float s = p;
#pragma unroll
  for (int o = 1; o < 64; o <<= 1) s += __shfl_xor(s, o);
  if ((e & 63) == 0) red[e >> 6] = s;
  __syncthreads();
  float tot = red[0] + red[1] + red[2] + red[3];
  out_align[((size_t)b * 800 + t) * 256 + e] = p / tot;
}

// ---------------- context -> inp1c[:,256:1152] ----------------
__global__ __launch_bounds__(256) void k_ctx(const float* __restrict__ cvec,
                                             const float* __restrict__ coef,
                                             const float* __restrict__ inv2,
                                             const float* __restrict__ mem,
                                             unsigned short* inp1c,
                                             int t0, int tbeg, int tend) {
  __shared__ float wl[4096];
  __shared__ float rinv[16];
  int b = blockIdx.y, tB = tbeg + blockIdx.x * 16, tid = threadIdx.x;
  int nt = tend - tB; if (nt > 16) nt = 16;
  float cv = cvec[b * 256 + tid], co = coef[b * 256 + tid], iv = inv2[b * 256 + tid];
  for (int s = 0; s < nt; ++s) {
    float d = (float)(tB + s) - cv;
    wl[s * 256 + tid] = co * __expf(-d * d * iv) + 1e-5f;
  }
  for (int s = nt; s < 16; ++s) wl[s * 256 + tid] = 0.f;
  __syncthreads();
  int wv = tid >> 6, ln = tid & 63;
  for (int s = wv; s < nt; s += 4) {
    float x = wl[s * 256 + ln] + wl[s * 256 + 64 + ln] + wl[s * 256 + 128 + ln] + wl[s * 256 + 192 + ln];
#pragma unroll
    for (int o = 1; o < 64; o <<= 1) x += __shfl_xor(x, o);
    if (ln == 0) rinv[s] = 1.f / x;
  }
  __syncthreads();
  for (int s = 0; s < nt; ++s) wl[s * 256 + tid] *= rinv[s];
  __syncthreads();
  float acc[16][4];
#pragma unroll
  for (int s = 0; s < 16; ++s) { acc[s][0] = 0.f; acc[s][1] = 0.f; acc[s][2] = 0.f; acc[s][3] = 0.f; }
  for (int e = 0; e < 256; ++e) {
    const float* mrow = mem + ((size_t)b * 256 + e) * 896;
    float m0 = mrow[tid], m1 = mrow[tid + 256], m2 = mrow[tid + 512];
    float m3 = (tid < 128) ? mrow[tid + 768] : 0.f;
#pragma unroll
    for (int s = 0; s < 16; ++s) {
      float w = wl[s * 256 + e];
      acc[s][0] += w * m0; acc[s][1] += w * m1; acc[s][2] += w * m2; acc[s][3] += w * m3;
    }
  }
  for (int s = 0; s < nt; ++s) {
    size_t base = ((size_t)(tB - t0 + s) * 32 + b) * 1280 + 256;
    inp1c[base + tid]       = f2b(acc[s][0]);
    inp1c[base + tid + 256] = f2b(acc[s][1]);
    inp1c[base + tid + 512] = f2b(acc[s][2]);
    if (tid < 128) inp1c[base + tid + 768] = f2b(acc[s][3]);
  }
}

// ---------------- PE gather -> inp1c[:,1152:1280] ----------------
__global__ void k_pegather(const int* __restrict__ dfi, const float* __restrict__ pe,
                           unsigned short* inp1c, int t0, int tbeg, int R) {
  int idx = blockIdx.x * 256 + threadIdx.x;
  if (idx >= R * 4096) return;
  int d = idx & 127, r = idx >> 7;
  int b = r & 31, ti = r >> 5;
  int t = tbeg + ti;
  int pos = dfi[b * 800 + t];
  inp1c[((size_t)(t - t0) * 32 + b) * 1280 + 1152 + d] = f2b(pe[pos * 128 + d]);
}

// ---------------- Wih1 fp32 -> bf16 (round-nearest), [4096][1280] ----------------
__global__ void k_repackW(const float* __restrict__ Wih1, unsigned short* wbf) {
  int idx = blockIdx.x * 256 + threadIdx.x;
  if (idx >= 1310720) return;
  float4 f = *(const float4*)(Wih1 + (size_t)idx * 4);
  union { unsigned short us[4]; unsigned long long q; } o;
  o.us[0] = f2b(f.x); o.us[1] = f2b(f.y); o.us[2] = f2b(f.z); o.us[3] = f2b(f.w);
  *(unsigned long long*)(wbf + (size_t)idx * 4) = o.q;
}

// ---------------- per-WG B-frag images (64 WGs x 16 dims) -> global wimg ----------------
// wimg[wg][mat][g][ks][lane][e]; mat: 0=Whh1 1=Wih2 2=Whh2; row = g*1024 + wg*16 + (lane&15)
__global__ void k_repackImg(const float* __restrict__ Whh1, const float* __restrict__ Wih2,
                            const float* __restrict__ Whh2, unsigned short* wimg) {
  size_t idx = (size_t)blockIdx.x * 256 + threadIdx.x;
  if (idx >= 12582912ull) return;
  int wg  = (int)(idx / 196608);
  int r   = (int)(idx % 196608);
  int mat = r / 65536;
  int r2  = r % 65536;
  int g   = r2 >> 14;
  int r3  = r2 & 16383;
  int ks  = r3 >> 9;
  int l   = (r3 >> 3) & 63;
  int e   = r3 & 7;
  int nn = l & 15, kq = l >> 4;
  int row = g * 1024 + wg * 16 + nn;
  int kk = ks * 32 + kq * 8 + e;
  const float* W = (mat == 0) ? Whh1 : (mat == 1) ? Wih2 : Whh2;
  wimg[idx] = f2b(W[(size_t)row * 1024 + kk]);
}

// ---------------- melpre[t][b][c] = ctx_pe . Wproj[c,1024:2048] + bproj[c] ----------------
__global__ __launch_bounds__(256) void k_melpre(const unsigned short* __restrict__ inp1c,
                                                const float* __restrict__ Wproj,
                                                const float* __restrict__ bproj,
                                                unsigned short* melpre, int t0, int tbeg) {
  extern __shared__ unsigned short ctx[];  // 32*1024 bf16
  int t = tbeg + blockIdx.x, tid = threadIdx.x;
  int tt = t - t0;
  for (int i = tid; i < 32768; i += 256)
    ctx[i] = inp1c[((size_t)tt * 32 + (i >> 10)) * 1280 + 256 + (i & 1023)];
  __syncthreads();
  if (tid < 240) {
    int c = tid % 80, bs = tid / 80;
    const float* w = Wproj + (size_t)c * 2048 + 1024;
    for (int b = bs; b < 32; b += 3) {
      float s = bproj[c];
      const unsigned short* x = ctx + b * 1024;
#pragma unroll 8
      for (int kk = 0; kk < 1024; ++kk) s += b2f(x[kk]) * w[kk];
      melpre[((size_t)t * 32 + b) * 80 + c] = f2b(s);
    }
  }
}

// 8 L2-bypassing (coherent) 16B loads in flight, one drain.
#define COH_LOAD8(d0,d1,d2,d3,d4,d5,d6,d7, p0,p1,p2,p3,p4,p5,p6,p7)       \
  asm volatile(                                                            \
    "global_load_dwordx4 %0, %8, off sc0 sc1\n\t"                          \
    "global_load_dwordx4 %1, %9, off sc0 sc1\n\t"                          \
    "global_load_dwordx4 %2, %10, off sc0 sc1\n\t"                         \
    "global_load_dwordx4 %3, %11, off sc0 sc1\n\t"                         \
    "global_load_dwordx4 %4, %12, off sc0 sc1\n\t"                         \
    "global_load_dwordx4 %5, %13, off sc0 sc1\n\t"                         \
    "global_load_dwordx4 %6, %14, off sc0 sc1\n\t"                         \
    "global_load_dwordx4 %7, %15, off sc0 sc1\n\t"                         \
    "s_waitcnt vmcnt(0)"                                                   \
    : "=&v"(d0), "=&v"(d1), "=&v"(d2), "=&v"(d3),                          \
      "=&v"(d4), "=&v"(d5), "=&v"(d6), "=&v"(d7)                           \
    : "v"(p0), "v"(p1), "v"(p2), "v"(p3),                                  \
      "v"(p4), "v"(p5), "v"(p6), "v"(p7)                                   \
    : "memory")

// x-GEMM for step kn: wave g (=wid), 2 M-tiles, K=1280; into xa0/xa1
#define XGEMM(kn, gg_)                                                                \
  { xa0 = (f32x4){0.f,0.f,0.f,0.f}; xa1 = (f32x4){0.f,0.f,0.f,0.f};                   \
    int nn_ = lane & 15, kq_ = lane >> 4;                                             \
    int row_ = (gg_) * 1024 + wg * 16 + nn_;                                          \
    size_t tt_ = (size_t)((kn) - k0 + 2);                                             \
    const unsigned short* a0_ = A.inp1c + (tt_ * 32 + nn_) * 1280 + kq_ * 8;          \
    const unsigned short* a1_ = A.inp1c + (tt_ * 32 + 16 + nn_) * 1280 + kq_ * 8;     \
    const unsigned short* w_  = A.wbf + (size_t)row_ * 1280 + kq_ * 8;                \
    _Pragma("unroll 4")                                                               \
    for (int ks_ = 0; ks_ < 40; ++ks_) {                                              \
      bfrag8 bA_ = *(const bfrag8*)(w_ + ks_ * 32);                                   \
      bfrag8 aA_ = *(const bfrag8*)(a0_ + ks_ * 32);                                  \
      bfrag8 aB_ = *(const bfrag8*)(a1_ + ks_ * 32);                                  \
      xa0 = __builtin_amdgcn_mfma_f32_16x16x32_bf16(aA_, bA_, xa0, 0, 0, 0);          \
      xa1 = __builtin_amdgcn_mfma_f32_16x16x32_bf16(aB_, bA_, xa1, 0, 0, 0);          \
    } }

// h-MFMA over a staged LDS buffer (hoff) against global B-frags bp; 2 M-tiles
#define HMFMA(hoff, bp)                                                               \
  { int nn_ = lane & 15, kq_ = lane >> 4;                                             \
    int sb0 = (hoff) + nn_ * 2048 + kq_ * 16;                                         \
    int sb1 = (hoff) + (16 + nn_) * 2048 + kq_ * 16;                                  \
    int sx0 = (nn_ & 7) << 4;                                                         \
    int sx1 = ((16 + nn_) & 7) << 4;                                                  \
    _Pragma("unroll")                                                                 \
    for (int ks_ = 0; ks_ < 32; ++ks_) {                                              \
      bfrag8 bb_ = (bp)[ks_ * 64];                                                    \
      ulonglong2 v0_ = *(const ulonglong2*)(smem + ((sb0 + ks_ * 64) ^ sx0));         \
      ulonglong2 v1_ = *(const ulonglong2*)(smem + ((sb1 + ks_ * 64) ^ sx1));         \
      union { unsigned long long q[2]; bfrag8 v; } ua_, ub_;                          \
      ua_.q[0] = v0_.x; ua_.q[1] = v0_.y;                                             \
      ub_.q[0] = v1_.x; ub_.q[1] = v1_.y;                                             \
      a0 = __builtin_amdgcn_mfma_f32_16x16x32_bf16(ua_.v, bb_, a0, 0, 0, 0);          \
      a1 = __builtin_amdgcn_mfma_f32_16x16x32_bf16(ub_.v, bb_, a1, 0, 0, 0);          \
    } }

// ---------------- persistent cooperative decoder: 64 WGs x 512 threads ----------------
struct DecArgs {
  const unsigned short* inp1c;
  const unsigned short* wbf;
  const unsigned short* wimg;
  const float* bih1; const float* bhh1; const float* bih2; const float* bhh2;
  const float* Wproj;
  const unsigned short* melpre;
  unsigned short* h1; unsigned short* h2; float* cst;
  unsigned int* cnt; float* out_mel;
  int k0, k1;
};

// LDS (dynamic 153088): h1s@0 (65536) | h2s@65536 (65536) | g1f@131072 (8704)
//   g2f@139776 (8704) | c1@148480 (2048) | c2@150528 (2048) | bias1@152576 | bias2@152832
__global__ __launch_bounds__(512, 1) void k_decode(DecArgs A) {
  extern __shared__ char smem[];
  float* g1f   = (float*)(smem + 131072);   // [32][68]
  float* g2f   = (float*)(smem + 139776);   // [32][68]
  float* c1    = (float*)(smem + 148480);   // [32][16]
  float* c2    = (float*)(smem + 150528);   // [32][16]
  float* bias1 = (float*)(smem + 152576);   // [64]
  float* bias2 = (float*)(smem + 152832);   // [64]

  int wg = blockIdx.x, tid = threadIdx.x;
  int wid = tid >> 6, lane = tid & 63;
  int k0 = A.k0, k1 = A.k1;
  const unsigned short* wimg_wg = A.wimg + (size_t)wg * 196608;

  if (tid < 64) {
    int g = tid >> 4, jj = tid & 15;
    int row = g * 1024 + wg * 16 + jj;
    bias1[tid] = A.bih1[row] + A.bhh1[row];
    bias2[tid] = A.bih2[row] + A.bhh2[row];
  }
  {
    int b = tid >> 4, jj = tid & 15;
    c1[b * 16 + jj] = (k0 == 0) ? 0.f : A.cst[((size_t)wg * 32 + b) * 16 + jj];
    c2[b * 16 + jj] = (k0 == 0) ? 0.f : A.cst[32768 + ((size_t)wg * 32 + b) * 16 + jj];
  }
  __syncthreads();

  f32x4 xa0 = {0.f,0.f,0.f,0.f}, xa1 = {0.f,0.f,0.f,0.f};
  if (wid < 4 && k0 < 800) XGEMM(k0, wid);

  long totspin = 0;
  for (int k = k0; k < k1; ++k) {
    bool do1 = (k < 800);
    bool do2 = (k >= 1 && k <= 800);

    // ---- stage h1[k-1] (slot (k-1)&1) and h2[k-2] (slot k&1) -> LDS, swizzled ----
    {
      const char* s1g = (const char*)(A.h1 + ((k - 1) & 1) * 32768);
      const char* s2g = (const char*)(A.h2 + (k & 1) * 32768);
      const char* p1 = s1g + tid * 16;
      const char* p2 = s2g + tid * 16;
      ulonglong2 d0,d1,d2,d3,d4,d5,d6,d7, e0,e1,e2,e3,e4,e5,e6,e7;
      COH_LOAD8(d0,d1,d2,d3,d4,d5,d6,d7,
                p1, p1+8192, p1+16384, p1+24576, p1+32768, p1+40960, p1+49152, p1+57344);
      COH_LOAD8(e0,e1,e2,e3,e4,e5,e6,e7,
                p2, p2+8192, p2+16384, p2+24576, p2+32768, p2+40960, p2+49152, p2+57344);
#define STG_WR(j, va, vb)                                            \
      { int m = (j)*512 + tid;                                       \
        int sw = (m * 16) ^ (((m >> 7) & 7) << 4);                   \
        *(ulonglong2*)(smem + sw) = va;                              \
        *(ulonglong2*)(smem + 65536 + sw) = vb; }
      STG_WR(0, d0, e0); STG_WR(1, d1, e1); STG_WR(2, d2, e2); STG_WR(3, d3, e3);
      STG_WR(4, d4, e4); STG_WR(5, d5, e5); STG_WR(6, d6, e6); STG_WR(7, d7, e7);
#undef STG_WR
    }
    __syncthreads();

    if (wid < 4) {
      int g = wid;
      if (do1) {
        f32x4 a0 = xa0, a1 = xa1;                       // x-part from barrier shadow
        const bfrag8* bp = (const bfrag8*)(wimg_wg) + g * 2048 + lane;   // Whh1
        HMFMA(0, bp);
        int nn = lane & 15, kq = lane >> 4;
#pragma unroll
        for (int q = 0; q < 4; ++q) {
          g1f[(kq * 4 + q) * 68 + g * 16 + nn]        = a0[q];
          g1f[(16 + kq * 4 + q) * 68 + g * 16 + nn]   = a1[q];
        }
      }
      // mel(k-2): cols 2*wg, 2*wg+1 from LDS-staged h2
      if (k >= 2 && wg < 40 && tid < 256) {
        int t = k - 2;
        int dot = tid >> 2, q = tid & 3;
        int col = 2 * wg + (dot >> 5), b = dot & 31;
        const float* wp = A.Wproj + (size_t)col * 2048 + q * 256;
        float s0 = 0.f, s1v = 0.f;
        int sbase = 65536 + b * 2048 + q * 512;
        int sxor = (b & 7) << 4;
#pragma unroll 8
        for (int ii = 0; ii < 32; ++ii) {
          ulonglong2 v = *(const ulonglong2*)(smem + ((sbase + ii * 16) ^ sxor));
          union { unsigned long long q; unsigned short u[4]; } a_, b2_;
          a_.q = v.x; b2_.q = v.y;
          const float* w0 = wp + ii * 8;
          s0  += b2f(a_.u[0])*w0[0] + b2f(a_.u[1])*w0[1] + b2f(a_.u[2])*w0[2] + b2f(a_.u[3])*w0[3];
          s1v += b2f(b2_.u[0])*w0[4] + b2f(b2_.u[1])*w0[5] + b2f(b2_.u[2])*w0[6] + b2f(b2_.u[3])*w0[7];
        }
        float s = s0 + s1v;
        s += __shfl_xor(s, 1);
        s += __shfl_xor(s, 2);
        if (q == 0) {
          float add = b2f(A.melpre[((size_t)t * 32 + b) * 80 + col]);
          A.out_mel[(size_t)b * 64000 + (size_t)col * 800 + t] = s + add;
        }
      }
    } else {
      int g = wid - 4;
      if (do2) {
        f32x4 a0 = {0.f,0.f,0.f,0.f}, a1 = {0.f,0.f,0.f,0.f};
        const bfrag8* bpA = (const bfrag8*)(wimg_wg) + 8192 + g * 2048 + lane;   // Wih2 (A=h1s)
        HMFMA(0, bpA);
        const bfrag8* bpB = (const bfrag8*)(wimg_wg) + 16384 + g * 2048 + lane;  // Whh2 (A=h2s)
        HMFMA(65536, bpB);
        int nn = lane & 15, kq = lane >> 4;
#pragma unroll
        for (int q = 0; q < 4; ++q) {
          g2f[(kq * 4 + q) * 68 + g * 16 + nn]        = a0[q];
          g2f[(16 + kq * 4 + q) * 68 + g * 16 + nn]   = a1[q];
        }
      }
    }
    __syncthreads();

    // ---- gates: all 512 threads; tid = b*16 + jj ----
    {
      int b = tid >> 4, jj = tid & 15;
      if (do1) {
        float gi = g1f[b * 68 + jj]      + bias1[jj];
        float gf = g1f[b * 68 + 16 + jj] + bias1[16 + jj];
        float gg = g1f[b * 68 + 32 + jj] + bias1[32 + jj];
        float go = g1f[b * 68 + 48 + jj] + bias1[48 + jj];
        float c = c1[b * 16 + jj];
        float cn = sigf(gf) * c + sigf(gi) * tanhf(gg);
        c1[b * 16 + jj] = cn;
        float hn = sigf(go) * tanhf(cn);
        float ho = __shfl_xor(hn, 1);
        if ((jj & 1) == 0) {
          unsigned int pk = (unsigned int)f2b(hn) | ((unsigned int)f2b(ho) << 16);
          __hip_atomic_store((unsigned int*)(A.h1 + (k & 1) * 32768 + b * 1024 + wg * 16 + jj), pk,
                             __ATOMIC_RELAXED, AGENT);
        }
      }
      if (do2) {
        float gi = g2f[b * 68 + jj]      + bias2[jj];
        float gf = g2f[b * 68 + 16 + jj] + bias2[16 + jj];
        float gg = g2f[b * 68 + 32 + jj] + bias2[32 + jj];
        float go = g2f[b * 68 + 48 + jj] + bias2[48 + jj];
        float c = c2[b * 16 + jj];
        float cn = sigf(gf) * c + sigf(gi) * tanhf(gg);
        c2[b * 16 + jj] = cn;
        float hn = sigf(go) * tanhf(cn);
        float ho = __shfl_xor(hn, 1);
        if ((jj & 1) == 0) {
          unsigned int pk = (unsigned int)f2b(hn) | ((unsigned int)f2b(ho) << 16);
          __hip_atomic_store((unsigned int*)(A.h2 + ((k - 1) & 1) * 32768 + b * 1024 + wg * 16 + jj), pk,
                             __ATOMIC_RELAXED, AGENT);
        }
      }
    }
    __syncthreads();   // drains vmcnt(0): h-stores committed before arrive
    if (tid == 0) {
      asm volatile("s_waitcnt vmcnt(0)" ::: "memory");
      __hip_atomic_fetch_add(A.cnt + (wg & 7) * 16, 1u, __ATOMIC_RELAXED, AGENT);
    }
    // next step's x-GEMM in the barrier shadow (waves 0-3; pollers in wave 7)
    if (wid < 4) {
      int kn = k + 1;
      if (kn < k1 && kn < 800) XGEMM(kn, wid);
    }
    if (tid >= 448 && tid < 456 && totspin >= 0) {
      int li = tid - 448;
      unsigned int tgt = (unsigned int)(k + 1) * 8u;
      while (__hip_atomic_load(A.cnt + li * 16, __ATOMIC_RELAXED, AGENT) < tgt) {
        __builtin_amdgcn_s_sleep(8);
        if (++totspin > (1l << 23)) {          // watchdog: record + free-run, never hang
          totspin = -1;
          __hip_atomic_fetch_add(A.cnt + 255, 1u, __ATOMIC_RELAXED, AGENT);
          break;
        }
      }
    }
    __syncthreads();
  }
  {
    int b = tid >> 4, jj = tid & 15;
    A.cst[((size_t)wg * 32 + b) * 16 + jj] = c1[b * 16 + jj];
    A.cst[32768 + ((size_t)wg * 32 + b) * 16 + jj] = c2[b * 16 + jj];
  }
}

// ---------------- diagnostics (fp32) ----------------
__global__ void k_diag(float* out_mel, float wsmb) {
  out_mel[0] = 1000.f + wsmb;                 // ~1000+MB => ws too small
}
__global__ void k_verify(const unsigned int* cnt, float* out_mel) {
  unsigned int tot = 0;
  for (int i = 0; i < 8; ++i) tot += cnt[i * 16];
  if (tot != 802u * 64u)
    out_mel[0] = 3000.f + (float)tot * (1.f / 64.f);          // ~3000+ => decode stalled
}

extern "C" void kernel_launch(void* const* d_in, const int* in_sizes, int n_in,
                              void* d_out, int out_size, void* d_ws, size_t ws_size,
                              hipStream_t stream) {
  const float* memory = (const float*)d_in[0];
  const float* dur    = (const float*)d_in[1];
  const int*   dfi    = (const int*)d_in[2];
  const float* range  = (const float*)d_in[3];
  const float* din    = (const float*)d_in[4];
  const float* Wp1    = (const float*)d_in[6];
  const float* Wp2    = (const float*)d_in[7];
  const float* Wih1   = (const float*)d_in[8];
  const float* Whh1   = (const float*)d_in[9];
  const float* bih1   = (const float*)d_in[10];
  const float* bhh1   = (const float*)d_in[11];
  const float* Wih2   = (const float*)d_in[12];
  const float* Whh2   = (const float*)d_in[13];
  const float* bih2   = (const float*)d_in[14];
  const float* bhh2   = (const float*)d_in[15];
  const float* Wproj  = (const float*)d_in[16];
  const float* bproj  = (const float*)d_in[17];
  const float* u1     = (const float*)d_in[18];
  const float* u2     = (const float*)d_in[19];

  char* ws = (char*)d_ws;
  unsigned int* cnt   = (unsigned int*)ws;
  float* cvec         = (float*)(ws + 4096);
  float* coef         = cvec + 8192;
  float* inv2         = coef + 8192;
  float* pe           = (float*)(ws + 102400);
  unsigned short* h1  = (unsigned short*)(ws + 153600);
  unsigned short* h2  = h1 + 65536;
  float* cst          = (float*)(ws + 415744);
  unsigned short* melpre = (unsigned short*)(ws + 720896);
  unsigned short* wbf    = (unsigned short*)(ws + 4849664);
  unsigned short* wimg   = (unsigned short*)(ws + 15728640);
  unsigned short* inp1c  = (unsigned short*)(ws + 41943040ull);

  float* out_mel   = (float*)d_out;                         // fp32 outputs (reference dtype)
  float* out_align = out_mel + 2048000;

  const size_t BASE = 41943040ull;
  int TC;
  if      (ws_size >= BASE + 802ull * 81920ull) TC = 800;
  else if (ws_size >= BASE + 202ull * 81920ull) TC = 200;
  else if (ws_size >= BASE +  82ull * 81920ull) TC = 80;
  else if (ws_size >= BASE +  42ull * 81920ull) TC = 40;
  else {
    k_diag<<<1, 1, 0, stream>>>(out_mel, (float)(ws_size >> 20));
    return;
  }

  hipFuncSetAttribute((const void*)k_decode, hipFuncAttributeMaxDynamicSharedMemorySize, 153088);
  hipFuncSetAttribute((const void*)k_melpre, hipFuncAttributeMaxDynamicSharedMemorySize, 98304);

  k_init<<<256, 256, 0, stream>>>((unsigned int*)(ws + 153600), cnt, pe);
  k_attn_prep<<<32, 256, 0, stream>>>(dur, range, cvec, coef, inv2);
  k_attn<<<dim3(800, 32), 256, 0, stream>>>(cvec, coef, inv2, out_align);
  k_repackW<<<5120, 256, 0, stream>>>(Wih1, wbf);
  k_repackImg<<<49152, 256, 0, stream>>>(Whh1, Wih2, Whh2, wimg);

  DecArgs da[20];
  int nch = (800 + TC - 1) / TC;
  for (int c = 0; c < nch; ++c) {
    int k0 = c * TC;
    int k1 = (c == nch - 1) ? 802 : (c + 1) * TC;
    int t0 = k0 - 2;
    int tbeg = t0 < 0 ? 0 : t0;
    int tend = k1 < 800 ? k1 : 800;
    int R = tend - tbeg;
    k_prenet<<<R, 256, 0, stream>>>(din, u1, u2, Wp1, Wp2, inp1c, t0, tbeg);
    k_ctx<<<dim3((R + 15) / 16, 32), 256, 0, stream>>>(cvec, coef, inv2, memory, inp1c, t0, tbeg, tend);
    k_pegather<<<(R * 4096 + 255) / 256, 256, 0, stream>>>(dfi, pe, inp1c, t0, tbeg, R);
    k_melpre<<<R, 256, 65536, stream>>>(inp1c, Wproj, bproj, melpre, t0, tbeg);

    da[c] = DecArgs{ inp1c, wbf, wimg, bih1, bhh1, bih2, bhh2,
                     Wproj, melpre, h1, h2, cst, cnt, out_mel, k0, k1 };
    void* kp[1] = { &da[c] };
    hipLaunchCooperativeKernel((const void*)k_decode, dim3(64), dim3(512), kp, 153088, stream);
  }
  k_verify<<<1, 1, 0, stream>>>(cnt, out_mel);
}

// Round 14
// 27023.428 us; speedup vs baseline: 1.4779x; 1.4779x over previous
//
#include <hip/hip_runtime.h>
#include <hip/hip_bf16.h>
#include <math.h>

typedef __attribute__((ext_vector_type(8))) short bfrag8;   // 8 x bf16
typedef __attribute__((ext_vector_type(4))) float f32x4;    // MFMA accumulator
#define AGENT __HIP_MEMORY_SCOPE_AGENT

static __device__ __forceinline__ float b2f(unsigned short u) {
  union { unsigned int i; float f; } v; v.i = ((unsigned int)u) << 16; return v.f;
}
static __device__ __forceinline__ unsigned short f2b(float f) {
  union { float f; unsigned int i; } v; v.f = f;
  unsigned int i = v.i;
  return (unsigned short)((i + 0x7FFFu + ((i >> 16) & 1u)) >> 16);
}
static __device__ __forceinline__ float sigf(float x) { return 1.f / (1.f + __expf(-x)); }

// ---------------- workspace layout (bytes) ----------------
// cnt    [0,1024)        barrier lines (16 x 64B) + cnt[255] = watchdog
// scan   [4096,102400)   cvec/coef/inv2
// pe     [102400,153600)
// h1     [153600,284672) 2 slots x 64KB, WG-MAJOR: h[wg*128 + b*4 + jj] (bf16)
// h2     [284672,415744)
// cst    [415744,677888)
// melpre @ 720896        (4,096,000)
// wbf    @ 4,849,664     (10,485,760)  Wih1 bf16 [4096][1280]
// wimg   @ 15,728,640    (25,165,824)  per-WG B-frag images [256][3][2048][8]
// inp1c  @ 41,943,040    ((TC+2) x 81920)

// ---------------- init ----------------
__global__ void k_init(unsigned int* hzero, unsigned int* cnt, float* pe) {
  int idx = blockIdx.x * 256 + threadIdx.x;
  if (idx < 256) cnt[idx] = 0u;
  if (idx < 65536) hzero[idx] = 0u;                     // h1+h2 both slots
  if (idx < 6400) {
    int p = idx >> 6, i = idx & 63;
    float freq = __expf(-(float)(2 * i) * 0.0719557842162201f); // ln(10000)/128
    float a = (float)p * freq;
    pe[p * 128 + 2 * i]     = sinf(a);
    pe[p * 128 + 2 * i + 1] = cosf(a);
  }
}

// ---------------- prenet -> inp1c[:, 0:256] ----------------
__global__ __launch_bounds__(256) void k_prenet(const float* __restrict__ din,
                                                const float* __restrict__ u1,
                                                const float* __restrict__ u2,
                                                const float* __restrict__ Wp1,
                                                const float* __restrict__ Wp2,
                                                unsigned short* inp1c, int t0, int tbeg) {
  __shared__ float dec[2560];
  __shared__ float X1[8192];
  int t = tbeg + blockIdx.x, tid = threadIdx.x;
  int tt = t - t0;
  for (int i = tid; i < 2560; i += 256) {
    int b = i / 80, f = i % 80;
    dec[i] = (t == 0) ? 0.f : din[((size_t)b * 80 + f) * 800 + (t - 1)];
  }
  __syncthreads();
  int n = tid;
  for (int b = 0; b < 32; ++b) {
    float s = 0.f;
    const float* w = Wp1 + n * 80;
    const float* d = dec + b * 80;
#pragma unroll 8
    for (int f = 0; f < 80; ++f) s += d[f] * w[f];
    s = fmaxf(s, 0.f);
    float m = (u1[((size_t)t * 32 + b) * 256 + n] >= 0.5f) ? 2.f : 0.f;
    X1[b * 256 + n] = s * m;
  }
  __syncthreads();
  for (int b = 0; b < 32; ++b) {
    float s = 0.f;
    const float* w = Wp2 + n * 256;
    const float* x = X1 + b * 256;
#pragma unroll 8
    for (int kk = 0; kk < 256; ++kk) s += x[kk] * w[kk];
    s = fmaxf(s, 0.f);
    float m = (u2[((size_t)t * 32 + b) * 256 + n] >= 0.5f) ? 2.f : 0.f;
    inp1c[((size_t)tt * 32 + b) * 1280 + n] = f2b(s * m);
  }
}

// ---------------- attention precompute ----------------
__global__ __launch_bounds__(256) void k_attn_prep(const float* __restrict__ dur,
                                                   const float* __restrict__ range,
                                                   float* cvec, float* coef, float* inv2) {
  __shared__ float s[256];
  int b = blockIdx.x, e = threadIdx.x;
  float d = dur[b * 256 + e];
  s[e] = d;
  __syncthreads();
  for (int off = 1; off < 256; off <<= 1) {
    float v = (e >= off) ? s[e - off] : 0.f;
    __syncthreads();
    s[e] = s[e] + v;
    __syncthreads();
  }
  float c = s[e] - 0.5f * d;
  float sg = range[b * 256 + e] + 1e-5f;
  cvec[b * 256 + e] = c;
  coef[b * 256 + e] = rsqrtf(6.283185307179586f * sg * sg);
  inv2[b * 256 + e] = 1.f / (2.f * sg * sg);
}

// ---------------- alignments output (fp32) ----------------
__global__ __launch_bounds__(256) void k_attn(const float* __restrict__ cvec,
                                              const float* __restrict__ coef,
                                              const float* __restrict__ inv2,
                                              float* out_align) {
  __shared__ float red[4];
  int t = blockIdx.x, b = blockIdx.y, e = threadIdx.x;
  float dt = (float)t - cvec[b * 256 + e];
  float p = coef[b * 256 + e] * __expf(-dt * dt * inv2[b * 256 + e]) + 1e-5f;
  float s = p;
#pragma unroll
  for (int o = 1; o < 64; o <<= 1) s += __shfl_xor(s, o);
  if ((e & 63) == 0) red[e >> 6] = s;
  __syncthreads();
  float tot = red[0] + red[1] + red[2] + red[3];
  out_align[((size_t)b * 800 + t) * 256 + e] = p / tot;
}

// ---------------- context -> inp1c[:,256:1152] ----------------
__global__ __launch_bounds__(256) void k_ctx(const float* __restrict__ cvec,
                                             const float* __restrict__ coef,
                                             const float* __restrict__ inv2,
                                             const float* __restrict__ mem,
                                             unsigned short* inp1c,
                                             int t0, int tbeg, int tend) {
  __shared__ float wl[4096];
  __shared__ float rinv[16];
  int b = blockIdx.y, tB = tbeg + blockIdx.x * 16, tid = threadIdx.x;
  int nt = tend - tB; if (nt > 16) nt = 16;
  float cv = cvec[b * 256 + tid], co = coef[b * 256 + tid], iv = inv2[b * 256 + tid];
  for (int s = 0; s < nt; ++s) {
    float d = (float)(tB + s) - cv;
    wl[s * 256 + tid] = co * __expf(-d * d * iv) + 1e-5f;
  }
  for (int s = nt; s < 16; ++s) wl[s * 256 + tid] = 0.f;
  __syncthreads();
  int wv = tid >> 6, ln = tid & 63;
  for (int s = wv; s < nt; s += 4) {
    float x = wl[s * 256 + ln] + wl[s * 256 + 64 + ln] + wl[s * 256 + 128 + ln] + wl[s * 256 + 192 + ln];
#pragma unroll
    for (int o = 1; o < 64; o <<= 1) x += __shfl_xor(x, o);
    if (ln == 0) rinv[s] = 1.f / x;
  }
  __syncthreads();
  for (int s = 0; s < nt; ++s) wl[s * 256 + tid] *= rinv[s];
  __syncthreads();
  float acc[16][4];
#pragma unroll
  for (int s = 0; s < 16; ++s) { acc[s][0] = 0.f; acc[s][1] = 0.f; acc[s][2] = 0.f; acc[s][3] = 0.f; }
  for (int e = 0; e < 256; ++e) {
    const float* mrow = mem + ((size_t)b * 256 + e) * 896;
    float m0 = mrow[tid], m1 = mrow[tid + 256], m2 = mrow[tid + 512];
    float m3 = (tid < 128) ? mrow[tid + 768] : 0.f;
#pragma unroll
    for (int s = 0; s < 16; ++s) {
      float w = wl[s * 256 + e];
      acc[s][0] += w * m0; acc[s][1] += w * m1; acc[s][2] += w * m2; acc[s][3] += w * m3;
    }
  }
  for (int s = 0; s < nt; ++s) {
    size_t base = ((size_t)(tB - t0 + s) * 32 + b) * 1280 + 256;
    inp1c[base + tid]       = f2b(acc[s][0]);
    inp1c[base + tid + 256] = f2b(acc[s][1]);
    inp1c[base + tid + 512] = f2b(acc[s][2]);
    if (tid < 128) inp1c[base + tid + 768] = f2b(acc[s][3]);
  }
}

// ---------------- PE gather -> inp1c[:,1152:1280] ----------------
__global__ void k_pegather(const int* __restrict__ dfi, const float* __restrict__ pe,
                           unsigned short* inp1c, int t0, int tbeg, int R) {
  int idx = blockIdx.x * 256 + threadIdx.x;
  if (idx >= R * 4096) return;
  int d = idx & 127, r = idx >> 7;
  int b = r & 31, ti = r >> 5;
  int t = tbeg + ti;
  int pos = dfi[b * 800 + t];
  inp1c[((size_t)(t - t0) * 32 + b) * 1280 + 1152 + d] = f2b(pe[pos * 128 + d]);
}

// ---------------- Wih1 fp32 -> bf16 (round-nearest), [4096][1280] ----------------
__global__ void k_repackW(const float* __restrict__ Wih1, unsigned short* wbf) {
  int idx = blockIdx.x * 256 + threadIdx.x;
  if (idx >= 1310720) return;
  float4 f = *(const float4*)(Wih1 + (size_t)idx * 4);
  union { unsigned short us[4]; unsigned long long q; } o;
  o.us[0] = f2b(f.x); o.us[1] = f2b(f.y); o.us[2] = f2b(f.z); o.us[3] = f2b(f.w);
  *(unsigned long long*)(wbf + (size_t)idx * 4) = o.q;
}

// ---------------- per-WG B-frag images -> global wimg (R1-verified mapping) ----------------
// wimg[wg][gi][ks][lane][e]; gi: 0=Whh1 1=Wih2 2=Whh2; row=(nn>>2)*1024+wg*4+(nn&3)
__global__ void k_repackImg(const float* __restrict__ Whh1, const float* __restrict__ Wih2,
                            const float* __restrict__ Whh2, unsigned short* wimg) {
  size_t idx = (size_t)blockIdx.x * 256 + threadIdx.x;
  if (idx >= 12582912ull) return;
  int wg = (int)(idx / 49152);
  int rem = (int)(idx % 49152);
  int gi = rem / 16384;
  int r2 = rem & 16383;
  int ks = r2 >> 9;
  int l  = (r2 >> 3) & 63;
  int e  = r2 & 7;
  int nn = l & 15, kq = l >> 4;
  int row = (nn >> 2) * 1024 + wg * 4 + (nn & 3);
  int kk = ks * 32 + kq * 8 + e;
  const float* W = (gi == 0) ? Whh1 : (gi == 1) ? Wih2 : Whh2;
  wimg[idx] = f2b(W[(size_t)row * 1024 + kk]);
}

// ---------------- melpre[t][b][c] = ctx_pe . Wproj[c,1024:2048] + bproj[c] ----------------
__global__ __launch_bounds__(256) void k_melpre(const unsigned short* __restrict__ inp1c,
                                                const float* __restrict__ Wproj,
                                                const float* __restrict__ bproj,
                                                unsigned short* melpre, int t0, int tbeg) {
  extern __shared__ unsigned short ctx[];  // 32*1024 bf16
  int t = tbeg + blockIdx.x, tid = threadIdx.x;
  int tt = t - t0;
  for (int i = tid; i < 32768; i += 256)
    ctx[i] = inp1c[((size_t)tt * 32 + (i >> 10)) * 1280 + 256 + (i & 1023)];
  __syncthreads();
  if (tid < 240) {
    int c = tid % 80, bs = tid / 80;
    const float* w = Wproj + (size_t)c * 2048 + 1024;
    for (int b = bs; b < 32; b += 3) {
      float s = bproj[c];
      const unsigned short* x = ctx + b * 1024;
#pragma unroll 8
      for (int kk = 0; kk < 1024; ++kk) s += b2f(x[kk]) * w[kk];
      melpre[((size_t)t * 32 + b) * 80 + c] = f2b(s);
    }
  }
}

// 8 L2-bypassing (coherent) 16B loads in flight, one drain.
#define COH_LOAD8(d0,d1,d2,d3,d4,d5,d6,d7, p0,p1,p2,p3,p4,p5,p6,p7)       \
  asm volatile(                                                            \
    "global_load_dwordx4 %0, %8, off sc0 sc1\n\t"                          \
    "global_load_dwordx4 %1, %9, off sc0 sc1\n\t"                          \
    "global_load_dwordx4 %2, %10, off sc0 sc1\n\t"                         \
    "global_load_dwordx4 %3, %11, off sc0 sc1\n\t"                         \
    "global_load_dwordx4 %4, %12, off sc0 sc1\n\t"                         \
    "global_load_dwordx4 %5, %13, off sc0 sc1\n\t"                         \
    "global_load_dwordx4 %6, %14, off sc0 sc1\n\t"                         \
    "global_load_dwordx4 %7, %15, off sc0 sc1\n\t"                         \
    "s_waitcnt vmcnt(0)"                                                   \
    : "=&v"(d0), "=&v"(d1), "=&v"(d2), "=&v"(d3),                          \
      "=&v"(d4), "=&v"(d5), "=&v"(d6), "=&v"(d7)                           \
    : "v"(p0), "v"(p1), "v"(p2), "v"(p3),                                  \
      "v"(p4), "v"(p5), "v"(p6), "v"(p7)                                   \
    : "memory")

// x-GEMM for step kn into xa0/xa1 (wid0-1; operands L2-cacheable)
#define XGEMM(kn)                                                                     \
  { xa0 = (f32x4){0.f,0.f,0.f,0.f}; xa1 = (f32x4){0.f,0.f,0.f,0.f};                   \
    int nn_ = lane & 15, kq_ = lane >> 4;                                             \
    int brow_ = wid * 16 + nn_;                                                       \
    int row_ = (nn_ >> 2) * 1024 + wg * 4 + (nn_ & 3);                                \
    size_t tt_ = (size_t)((kn) - k0 + 2);                                             \
    const unsigned short* arow_ = A.inp1c + (tt_ * 32 + brow_) * 1280 + kq_ * 8;      \
    const unsigned short* wrow_ = A.wbf + (size_t)row_ * 1280 + kq_ * 8;              \
    _Pragma("unroll 4")                                                               \
    for (int ks_ = 0; ks_ < 40; ks_ += 2) {                                           \
      bfrag8 aA_ = *(const bfrag8*)(arow_ + ks_ * 32);                                \
      bfrag8 aB_ = *(const bfrag8*)(arow_ + ks_ * 32 + 32);                           \
      bfrag8 b0_ = *(const bfrag8*)(wrow_ + ks_ * 32);                                \
      bfrag8 b1_ = *(const bfrag8*)(wrow_ + ks_ * 32 + 32);                           \
      xa0 = __builtin_amdgcn_mfma_f32_16x16x32_bf16(aA_, b0_, xa0, 0, 0, 0);          \
      xa1 = __builtin_amdgcn_mfma_f32_16x16x32_bf16(aB_, b1_, xa1, 0, 0, 0);          \
    } }

// MFMA over staged LDS h (hoff) vs global B-frags bp; single M-tile (brow)
#define HMFMA_LDS(hoff, bp, brow)                                                     \
  { int kq_ = lane >> 4;                                                              \
    int sb_ = (hoff) + (brow) * 2048 + kq_ * 16;                                      \
    int sx_ = ((brow) & 7) << 4;                                                      \
    _Pragma("unroll")                                                                 \
    for (int ks_ = 0; ks_ < 32; ks_ += 2) {                                           \
      ulonglong2 v0_ = *(const ulonglong2*)(smem + ((sb_ + ks_ * 64) ^ sx_));         \
      ulonglong2 v1_ = *(const ulonglong2*)(smem + ((sb_ + (ks_ + 1) * 64) ^ sx_));   \
      union { unsigned long long q[2]; bfrag8 v; } ua_, ub_;                          \
      ua_.q[0] = v0_.x; ua_.q[1] = v0_.y;                                             \
      ub_.q[0] = v1_.x; ub_.q[1] = v1_.y;                                             \
      a0 = __builtin_amdgcn_mfma_f32_16x16x32_bf16(ua_.v, (bp)[ks_ * 64], a0, 0, 0, 0); \
      a1 = __builtin_amdgcn_mfma_f32_16x16x32_bf16(ub_.v, (bp)[(ks_ + 1) * 64], a1, 0, 0, 0); } }

// ---------------- persistent cooperative decoder: 256 WGs x 512 ----------------
struct DecArgs {
  const unsigned short* inp1c;
  const unsigned short* wbf;
  const unsigned short* wimg;
  const float* bih1; const float* bhh1; const float* bih2; const float* bhh2;
  const float* Wproj;
  const unsigned short* melpre;
  unsigned short* h1; unsigned short* h2; float* cst;
  unsigned int* cnt; float* out_mel;
  int k0, k1;
};

// LDS (dynamic 139264): h1s@0 (65536, b-major swizzled) | h2s@65536 (65536)
//   g1@131072 (2176) | g2a@133248 | g2b@135424 | c1@137600 (512) | c2@138112 (512)
//   bias1@138624 (64) | bias2@138688 (64)
__global__ __launch_bounds__(512, 1) void k_decode(DecArgs A) {
  extern __shared__ char smem[];
  float (*g1)[17]  = (float(*)[17])(smem + 131072);
  float (*g2a)[17] = (float(*)[17])(smem + 133248);
  float (*g2b)[17] = (float(*)[17])(smem + 135424);
  float (*c1)[4]   = (float(*)[4])(smem + 137600);
  float (*c2)[4]   = (float(*)[4])(smem + 138112);
  float* bias1     = (float*)(smem + 138624);
  float* bias2     = (float*)(smem + 138688);

  int wg = blockIdx.x, tid = threadIdx.x;
  int wid = tid >> 6, lane = tid & 63;
  int k0 = A.k0, k1 = A.k1;
  const unsigned short* wimg_wg = A.wimg + (size_t)wg * 49152;

  if (tid < 16) {
    int row = (tid >> 2) * 1024 + wg * 4 + (tid & 3);
    bias1[tid] = A.bih1[row] + A.bhh1[row];
    bias2[tid] = A.bih2[row] + A.bhh2[row];
  }
  if (tid < 128) {
    int b = tid >> 2, jj = tid & 3;
    c1[b][jj] = (k0 == 0) ? 0.f : A.cst[((size_t)wg * 32 + b) * 4 + jj];
  } else if (tid < 256) {
    int b = (tid - 128) >> 2, jj = tid & 3;
    c2[b][jj] = (k0 == 0) ? 0.f : A.cst[32768 + ((size_t)wg * 32 + b) * 4 + jj];
  }
  __syncthreads();

  f32x4 xa0 = {0.f,0.f,0.f,0.f}, xa1 = {0.f,0.f,0.f,0.f};
  if (wid < 2 && k0 < 800) XGEMM(k0);

  long totspin = 0;
  for (int k = k0; k < k1; ++k) {
    bool do1 = (k < 800);
    bool do2 = (k >= 1 && k <= 800);

    // ---- stage h1[k-1] + h2[k-2] -> LDS, transposing wg-major -> b-major (swizzled) ----
    {
      const char* s1g = (const char*)(A.h1 + ((k - 1) & 1) * 32768);
      const char* s2g = (const char*)(A.h2 + (k & 1) * 32768);
      const char* p1 = s1g + tid * 16;
      const char* p2 = s2g + tid * 16;
      ulonglong2 d0,d1,d2,d3,d4,d5,d6,d7, e0,e1,e2,e3,e4,e5,e6,e7;
      COH_LOAD8(d0,d1,d2,d3,d4,d5,d6,d7,
                p1, p1+8192, p1+16384, p1+24576, p1+32768, p1+40960, p1+49152, p1+57344);
      COH_LOAD8(e0,e1,e2,e3,e4,e5,e6,e7,
                p2, p2+8192, p2+16384, p2+24576, p2+32768, p2+40960, p2+49152, p2+57344);
      // wg-major src: 16B chunk m covers wg_src=m>>4, b0=2*(m&15) (+1), dims wg_src*4..+3
#define STG_WR(j, va, vb)                                                          \
      { int m = (j)*512 + tid;                                                     \
        int wgs = m >> 4;                                                          \
        int b0 = (m & 15) * 2;                                                     \
        int a0_ = (b0 * 2048 + wgs * 8)       ^ ((b0 & 7) << 4);                   \
        int a1_ = ((b0 + 1) * 2048 + wgs * 8) ^ (((b0 + 1) & 7) << 4);             \
        *(unsigned long long*)(smem + a0_)         = va.x;                         \
        *(unsigned long long*)(smem + a1_)         = va.y;                         \
        *(unsigned long long*)(smem + 65536 + a0_) = vb.x;                         \
        *(unsigned long long*)(smem + 65536 + a1_) = vb.y; }
      STG_WR(0, d0, e0); STG_WR(1, d1, e1); STG_WR(2, d2, e2); STG_WR(3, d3, e3);
      STG_WR(4, d4, e4); STG_WR(5, d5, e5); STG_WR(6, d6, e6); STG_WR(7, d7, e7);
#undef STG_WR
    }
    __syncthreads();

    if (wid < 2) {
      if (do1) {
        int nn = lane & 15;
        int brow = wid * 16 + nn;
        f32x4 a0 = xa0, a1 = xa1;                       // x-part from barrier shadow
        const bfrag8* bp = (const bfrag8*)wimg_wg + lane;            // Whh1
        HMFMA_LDS(0, bp, brow);
        int kq = lane >> 4;
#pragma unroll
        for (int q = 0; q < 4; ++q) g1[wid * 16 + kq * 4 + q][nn] = (a0 + a1)[q];
      }
    } else if (wid < 4) {
      if (do2) {                                         // LSTM2 h1-part
        int mt = wid - 2;
        int nn = lane & 15;
        int brow = mt * 16 + nn;
        f32x4 a0 = {0.f,0.f,0.f,0.f}, a1 = {0.f,0.f,0.f,0.f};
        const bfrag8* bp = (const bfrag8*)wimg_wg + 2048 + lane;     // Wih2
        HMFMA_LDS(0, bp, brow);
        int kq = lane >> 4;
#pragma unroll
        for (int q = 0; q < 4; ++q) g2a[mt * 16 + kq * 4 + q][nn] = (a0 + a1)[q];
      }
    } else if (wid < 6) {
      if (do2) {                                         // LSTM2 h2-part
        int mt = wid - 4;
        int nn = lane & 15;
        int brow = mt * 16 + nn;
        f32x4 a0 = {0.f,0.f,0.f,0.f}, a1 = {0.f,0.f,0.f,0.f};
        const bfrag8* bp = (const bfrag8*)wimg_wg + 4096 + lane;     // Whh2
        HMFMA_LDS(65536, bp, brow);
        int kq = lane >> 4;
#pragma unroll
        for (int q = 0; q < 4; ++q) g2b[mt * 16 + kq * 4 + q][nn] = (a0 + a1)[q];
      }
    } else {
      if (k >= 2 && wg < 80) {                           // mel from LDS-staged h2
        int t = k - 2;
        int L = (wid - 6) * 64 + lane;
        int b = L >> 2, q = L & 3;
        const float* wp = A.Wproj + (size_t)wg * 2048 + q * 256;
        float s0 = 0.f, s1v = 0.f;
        int sbase = 65536 + b * 2048 + q * 512;
        int sxor = (b & 7) << 4;
#pragma unroll 8
        for (int ii = 0; ii < 32; ++ii) {
          ulonglong2 v = *(const ulonglong2*)(smem + ((sbase + ii * 16) ^ sxor));
          union { unsigned long long q; unsigned short u[4]; } a_, b2_;
          a_.q = v.x; b2_.q = v.y;
          const float* w0 = wp + ii * 8;
          s0  += b2f(a_.u[0])*w0[0] + b2f(a_.u[1])*w0[1] + b2f(a_.u[2])*w0[2] + b2f(a_.u[3])*w0[3];
          s1v += b2f(b2_.u[0])*w0[4] + b2f(b2_.u[1])*w0[5] + b2f(b2_.u[2])*w0[6] + b2f(b2_.u[3])*w0[7];
        }
        float s = s0 + s1v;
        s += __shfl_xor(s, 1);
        s += __shfl_xor(s, 2);
        if (q == 0) {
          float add = b2f(A.melpre[((size_t)t * 32 + b) * 80 + wg]);
          A.out_mel[(size_t)b * 64000 + (size_t)wg * 800 + t] = s + add;
        }
      }
    }
    __syncthreads();
    if (tid < 128) {
      if (do1) {
        int b = tid >> 2, jj = tid & 3;
        float gi = g1[b][jj]      + bias1[jj];
        float gf = g1[b][4 + jj]  + bias1[4 + jj];
        float gg = g1[b][8 + jj]  + bias1[8 + jj];
        float go = g1[b][12 + jj] + bias1[12 + jj];
        float c = c1[b][jj];
        float cn = sigf(gf) * c + sigf(gi) * tanhf(gg);
        c1[b][jj] = cn;
        float hn = sigf(go) * tanhf(cn);
        float ho = __shfl_xor(hn, 1);
        if ((jj & 1) == 0) {          // WG-MAJOR store: contiguous 512B block per WG
          unsigned int pk = (unsigned int)f2b(hn) | ((unsigned int)f2b(ho) << 16);
          __hip_atomic_store((unsigned int*)(A.h1 + (k & 1) * 32768 + wg * 128 + b * 4 + jj), pk,
                             __ATOMIC_RELAXED, AGENT);
        }
      }
    } else if (tid < 256) {
      if (do2) {
        int b = (tid - 128) >> 2, jj = tid & 3;
        float gi = g2a[b][jj]      + g2b[b][jj]      + bias2[jj];
        float gf = g2a[b][4 + jj]  + g2b[b][4 + jj]  + bias2[4 + jj];
        float gg = g2a[b][8 + jj]  + g2b[b][8 + jj]  + bias2[8 + jj];
        float go = g2a[b][12 + jj] + g2b[b][12 + jj] + bias2[12 + jj];
        float c = c2[b][jj];
        float cn = sigf(gf) * c + sigf(gi) * tanhf(gg);
        c2[b][jj] = cn;
        float hn = sigf(go) * tanhf(cn);
        float ho = __shfl_xor(hn, 1);
        if ((jj & 1) == 0) {
          unsigned int pk = (unsigned int)f2b(hn) | ((unsigned int)f2b(ho) << 16);
          __hip_atomic_store((unsigned int*)(A.h2 + ((k - 1) & 1) * 32768 + wg * 128 + b * 4 + jj), pk,
                             __ATOMIC_RELAXED, AGENT);
        }
      }
    }
    __syncthreads();   // drains vmcnt(0): h-stores committed before arrive
    if (tid == 0) {
      asm volatile("s_waitcnt vmcnt(0)" ::: "memory");
      __hip_atomic_fetch_add(A.cnt + (wg & 15) * 16, 1u, __ATOMIC_RELAXED, AGENT);
    }
    // next step's x-GEMM in the barrier shadow (wid0-1; pollers in wave 4)
    if (wid < 2) {
      int kn = k + 1;
      if (kn < k1 && kn < 800) XGEMM(kn);
    }
    if (tid >= 256 && tid < 272 && totspin >= 0) {
      int li = tid - 256;
      unsigned int tgt = (unsigned int)(k + 1) * 16u;
      while (__hip_atomic_load(A.cnt + li * 16, __ATOMIC_RELAXED, AGENT) < tgt) {
        __builtin_amdgcn_s_sleep(8);
        if (++totspin > (1l << 23)) {          // watchdog: record + free-run, never hang
          totspin = -1;
          __hip_atomic_fetch_add(A.cnt + 255, 1u, __ATOMIC_RELAXED, AGENT);
          break;
        }
      }
    }
    __syncthreads();
  }
  if (tid < 128) {
    int b = tid >> 2, jj = tid & 3;
    A.cst[((size_t)wg * 32 + b) * 4 + jj] = c1[b][jj];
  } else if (tid < 256) {
    int b = (tid - 128) >> 2, jj = tid & 3;
    A.cst[32768 + ((size_t)wg * 32 + b) * 4 + jj] = c2[b][jj];
  }
}

// ---------------- diagnostics (fp32) ----------------
__global__ void k_diag(float* out_mel, float wsmb) {
  out_mel[0] = 1000.f + wsmb;                 // ~1000+MB => ws too small
}
__global__ void k_verify(const unsigned int* cnt, float* out_mel) {
  unsigned int tot = 0;
  for (int i = 0; i < 16; ++i) tot += cnt[i * 16];
  if (tot != 802u * 256u)
    out_mel[0] = 3000.f + (float)tot * (1.f / 256.f);          // ~3000+ => decode stalled
}

extern "C" void kernel_launch(void* const* d_in, const int* in_sizes, int n_in,
                              void* d_out, int out_size, void* d_ws, size_t ws_size,
                              hipStream_t stream) {
  const float* memory = (const float*)d_in[0];
  const float* dur    = (const float*)d_in[1];
  const int*   dfi    = (const int*)d_in[2];
  const float* range  = (const float*)d_in[3];
  const float* din    = (const float*)d_in[4];
  const float* Wp1    = (const float*)d_in[6];
  const float* Wp2    = (const float*)d_in[7];
  const float* Wih1   = (const float*)d_in[8];
  const float* Whh1   = (const float*)d_in[9];
  const float* bih1   = (const float*)d_in[10];
  const float* bhh1   = (const float*)d_in[11];
  const float* Wih2   = (const float*)d_in[12];
  const float* Whh2   = (const float*)d_in[13];
  const float* bih2   = (const float*)d_in[14];
  const float* bhh2   = (const float*)d_in[15];
  const float* Wproj  = (const float*)d_in[16];
  const float* bproj  = (const float*)d_in[17];
  const float* u1     = (const float*)d_in[18];
  const float* u2     = (const float*)d_in[19];

  char* ws = (char*)d_ws;
  unsigned int* cnt   = (unsigned int*)ws;
  float* cvec         = (float*)(ws + 4096);
  float* coef         = cvec + 8192;
  float* inv2         = coef + 8192;
  float* pe           = (float*)(ws + 102400);
  unsigned short* h1  = (unsigned short*)(ws + 153600);
  unsigned short* h2  = h1 + 65536;
  float* cst          = (float*)(ws + 415744);
  unsigned short* melpre = (unsigned short*)(ws + 720896);
  unsigned short* wbf    = (unsigned short*)(ws + 4849664);
  unsigned short* wimg   = (unsigned short*)(ws + 15728640);
  unsigned short* inp1c  = (unsigned short*)(ws + 41943040ull);

  float* out_mel   = (float*)d_out;                         // fp32 outputs (reference dtype)
  float* out_align = out_mel + 2048000;

  const size_t BASE = 41943040ull;
  int TC;
  if      (ws_size >= BASE + 802ull * 81920ull) TC = 800;
  else if (ws_size >= BASE + 202ull * 81920ull) TC = 200;
  else if (ws_size >= BASE +  82ull * 81920ull) TC = 80;
  else if (ws_size >= BASE +  42ull * 81920ull) TC = 40;
  else {
    k_diag<<<1, 1, 0, stream>>>(out_mel, (float)(ws_size >> 20));
    return;
  }

  hipFuncSetAttribute((const void*)k_decode, hipFuncAttributeMaxDynamicSharedMemorySize, 147456);
  hipFuncSetAttribute((const void*)k_melpre, hipFuncAttributeMaxDynamicSharedMemorySize, 98304);

  k_init<<<256, 256, 0, stream>>>((unsigned int*)(ws + 153600), cnt, pe);
  k_attn_prep<<<32, 256, 0, stream>>>(dur, range, cvec, coef, inv2);
  k_attn<<<dim3(800, 32), 256, 0, stream>>>(cvec, coef, inv2, out_align);
  k_repackW<<<5120, 256, 0, stream>>>(Wih1, wbf);
  k_repackImg<<<49152, 256, 0, stream>>>(Whh1, Wih2, Whh2, wimg);

  DecArgs da[20];
  int nch = (800 + TC - 1) / TC;
  for (int c = 0; c < nch; ++c) {
    int k0 = c * TC;
    int k1 = (c == nch - 1) ? 802 : (c + 1) * TC;
    int t0 = k0 - 2;
    int tbeg = t0 < 0 ? 0 : t0;
    int tend = k1 < 800 ? k1 : 800;
    int R = tend - tbeg;
    k_prenet<<<R, 256, 0, stream>>>(din, u1, u2, Wp1, Wp2, inp1c, t0, tbeg);
    k_ctx<<<dim3((R + 15) / 16, 32), 256, 0, stream>>>(cvec, coef, inv2, memory, inp1c, t0, tbeg, tend);
    k_pegather<<<(R * 4096 + 255) / 256, 256, 0, stream>>>(dfi, pe, inp1c, t0, tbeg, R);
    k_melpre<<<R, 256, 65536, stream>>>(inp1c, Wproj, bproj, melpre, t0, tbeg);

    da[c] = DecArgs{ inp1c, wbf, wimg, bih1, bhh1, bih2, bhh2,
                     Wproj, melpre, h1, h2, cst, cnt, out_mel, k0, k1 };
    void* kp[1] = { &da[c] };
    hipLaunchCooperativeKernel((const void*)k_decode, dim3(256), dim3(512), kp, 139264, stream);
  }
  k_verify<<<1, 1, 0, stream>>>(cnt, out_mel);
}

// Round 15
// 21570.387 us; speedup vs baseline: 1.8515x; 1.2528x over previous
//
#include <hip/hip_runtime.h>
#include <hip/hip_bf16.h>
#include <math.h>

typedef __attribute__((ext_vector_type(8))) short bfrag8;   // 8 x bf16
typedef __attribute__((ext_vector_type(4))) float f32x4;    // MFMA accumulator
#define AGENT __HIP_MEMORY_SCOPE_AGENT

static __device__ __forceinline__ float b2f(unsigned short u) {
  union { unsigned int i; float f; } v; v.i = ((unsigned int)u) << 16; return v.f;
}
static __device__ __forceinline__ unsigned short f2b(float f) {
  union { float f; unsigned int i; } v; v.f = f;
  unsigned int i = v.i;
  return (unsigned short)((i + 0x7FFFu + ((i >> 16) & 1u)) >> 16);
}
static __device__ __forceinline__ float sigf(float x) { return 1.f / (1.f + __expf(-x)); }

// ---------------- workspace layout (bytes) ----------------
// cnt    [0,1024)        barrier lines (16 x 64B) + cnt[255] = watchdog
// scan   [4096,102400)   cvec/coef/inv2
// pe     [102400,153600)
// h1     [153600,284672) 2 slots x 32x1024 bf16 (b-major)
// h2     [284672,415744)
// cst    [415744,677888)
// melpre @ 720896        (4,096,000)
// wbf    @ 4,849,664     (10,485,760)  Wih1 bf16 [4096][1280]
// wimg1  @ 15,728,640    (8,388,608)   per-WG Whh1 B-frag images
// inp1c  @ 41,943,040    ((TC+2) x 81920)

// ---------------- init ----------------
__global__ void k_init(unsigned int* hzero, unsigned int* cnt, float* pe) {
  int idx = blockIdx.x * 256 + threadIdx.x;
  if (idx < 256) cnt[idx] = 0u;
  if (idx < 65536) hzero[idx] = 0u;                     // h1+h2 both slots
  if (idx < 6400) {
    int p = idx >> 6, i = idx & 63;
    float freq = __expf(-(float)(2 * i) * 0.0719557842162201f); // ln(10000)/128
    float a = (float)p * freq;
    pe[p * 128 + 2 * i]     = sinf(a);
    pe[p * 128 + 2 * i + 1] = cosf(a);
  }
}

// ---------------- prenet -> inp1c[:, 0:256] ----------------
__global__ __launch_bounds__(256) void k_prenet(const float* __restrict__ din,
                                                const float* __restrict__ u1,
                                                const float* __restrict__ u2,
                                                const float* __restrict__ Wp1,
                                                const float* __restrict__ Wp2,
                                                unsigned short* inp1c, int t0, int tbeg) {
  __shared__ float dec[2560];
  __shared__ float X1[8192];
  int t = tbeg + blockIdx.x, tid = threadIdx.x;
  int tt = t - t0;
  for (int i = tid; i < 2560; i += 256) {
    int b = i / 80, f = i % 80;
    dec[i] = (t == 0) ? 0.f : din[((size_t)b * 80 + f) * 800 + (t - 1)];
  }
  __syncthreads();
  int n = tid;
  for (int b = 0; b < 32; ++b) {
    float s = 0.f;
    const float* w = Wp1 + n * 80;
    const float* d = dec + b * 80;
#pragma unroll 8
    for (int f = 0; f < 80; ++f) s += d[f] * w[f];
    s = fmaxf(s, 0.f);
    float m = (u1[((size_t)t * 32 + b) * 256 + n] >= 0.5f) ? 2.f : 0.f;
    X1[b * 256 + n] = s * m;
  }
  __syncthreads();
  for (int b = 0; b < 32; ++b) {
    float s = 0.f;
    const float* w = Wp2 + n * 256;
    const float* x = X1 + b * 256;
#pragma unroll 8
    for (int kk = 0; kk < 256; ++kk) s += x[kk] * w[kk];
    s = fmaxf(s, 0.f);
    float m = (u2[((size_t)t * 32 + b) * 256 + n] >= 0.5f) ? 2.f : 0.f;
    inp1c[((size_t)tt * 32 + b) * 1280 + n] = f2b(s * m);
  }
}

// ---------------- attention precompute ----------------
__global__ __launch_bounds__(256) void k_attn_prep(const float* __restrict__ dur,
                                                   const float* __restrict__ range,
                                                   float* cvec, float* coef, float* inv2) {
  __shared__ float s[256];
  int b = blockIdx.x, e = threadIdx.x;
  float d = dur[b * 256 + e];
  s[e] = d;
  __syncthreads();
  for (int off = 1; off < 256; off <<= 1) {
    float v = (e >= off) ? s[e - off] : 0.f;
    __syncthreads();
    s[e] = s[e] + v;
    __syncthreads();
  }
  float c = s[e] - 0.5f * d;
  float sg = range[b * 256 + e] + 1e-5f;
  cvec[b * 256 + e] = c;
  coef[b * 256 + e] = rsqrtf(6.283185307179586f * sg * sg);
  inv2[b * 256 + e] = 1.f / (2.f * sg * sg);
}

// ---------------- alignments output (fp32) ----------------
__global__ __launch_bounds__(256) void k_attn(const float* __restrict__ cvec,
                                              const float* __restrict__ coef,
                                              const float* __restrict__ inv2,
                                              float* out_align) {
  __shared__ float red[4];
  int t = blockIdx.x, b = blockIdx.y, e = threadIdx.x;
  float dt = (float)t - cvec[b * 256 + e];
  float p = coef[b * 256 + e] * __expf(-dt * dt * inv2[b * 256 + e]) + 1e-5f;
  float s = p;
#pragma unroll
  for (int o = 1; o < 64; o <<= 1) s += __shfl_xor(s, o);
  if ((e & 63) == 0) red[e >> 6] = s;
  __syncthreads();
  float tot = red[0] + red[1] + red[2] + red[3];
  out_align[((size_t)b * 800 + t) * 256 + e] = p / tot;
}

// ---------------- context -> inp1c[:,256:1152] ----------------
__global__ __launch_bounds__(256) void k_ctx(const float* __restrict__ cvec,
                                             const float* __restrict__ coef,
                                             const float* __restrict__ inv2,
                                             const float* __restrict__ mem,
                                             unsigned short* inp1c,
                                             int t0, int tbeg, int tend) {
  __shared__ float wl[4096];
  __shared__ float rinv[16];
  int b = blockIdx.y, tB = tbeg + blockIdx.x * 16, tid = threadIdx.x;
  int nt = tend - tB; if (nt > 16) nt = 16;
  float cv = cvec[b * 256 + tid], co = coef[b * 256 + tid], iv = inv2[b * 256 + tid];
  for (int s = 0; s < nt; ++s) {
    float d = (float)(tB + s) - cv;
    wl[s * 256 + tid] = co * __expf(-d * d * iv) + 1e-5f;
  }
  for (int s = nt; s < 16; ++s) wl[s * 256 + tid] = 0.f;
  __syncthreads();
  int wv = tid >> 6, ln = tid & 63;
  for (int s = wv; s < nt; s += 4) {
    float x = wl[s * 256 + ln] + wl[s * 256 + 64 + ln] + wl[s * 256 + 128 + ln] + wl[s * 256 + 192 + ln];
#pragma unroll
    for (int o = 1; o < 64; o <<= 1) x += __shfl_xor(x, o);
    if (ln == 0) rinv[s] = 1.f / x;
  }
  __syncthreads();
  for (int s = 0; s < nt; ++s) wl[s * 256 + tid] *= rinv[s];
  __syncthreads();
  float acc[16][4];
#pragma unroll
  for (int s = 0; s < 16; ++s) { acc[s][0] = 0.f; acc[s][1] = 0.f; acc[s][2] = 0.f; acc[s][3] = 0.f; }
  for (int e = 0; e < 256; ++e) {
    const float* mrow = mem + ((size_t)b * 256 + e) * 896;
    float m0 = mrow[tid], m1 = mrow[tid + 256], m2 = mrow[tid + 512];
    float m3 = (tid < 128) ? mrow[tid + 768] : 0.f;
#pragma unroll
    for (int s = 0; s < 16; ++s) {
      float w = wl[s * 256 + e];
      acc[s][0] += w * m0; acc[s][1] += w * m1; acc[s][2] += w * m2; acc[s][3] += w * m3;
    }
  }
  for (int s = 0; s < nt; ++s) {
    size_t base = ((size_t)(tB - t0 + s) * 32 + b) * 1280 + 256;
    inp1c[base + tid]       = f2b(acc[s][0]);
    inp1c[base + tid + 256] = f2b(acc[s][1]);
    inp1c[base + tid + 512] = f2b(acc[s][2]);
    if (tid < 128) inp1c[base + tid + 768] = f2b(acc[s][3]);
  }
}

// ---------------- PE gather -> inp1c[:,1152:1280] ----------------
__global__ void k_pegather(const int* __restrict__ dfi, const float* __restrict__ pe,
                           unsigned short* inp1c, int t0, int tbeg, int R) {
  int idx = blockIdx.x * 256 + threadIdx.x;
  if (idx >= R * 4096) return;
  int d = idx & 127, r = idx >> 7;
  int b = r & 31, ti = r >> 5;
  int t = tbeg + ti;
  int pos = dfi[b * 800 + t];
  inp1c[((size_t)(t - t0) * 32 + b) * 1280 + 1152 + d] = f2b(pe[pos * 128 + d]);
}

// ---------------- Wih1 fp32 -> bf16 (round-nearest), [4096][1280] ----------------
__global__ void k_repackW(const float* __restrict__ Wih1, unsigned short* wbf) {
  int idx = blockIdx.x * 256 + threadIdx.x;
  if (idx >= 1310720) return;
  float4 f = *(const float4*)(Wih1 + (size_t)idx * 4);
  union { unsigned short us[4]; unsigned long long q; } o;
  o.us[0] = f2b(f.x); o.us[1] = f2b(f.y); o.us[2] = f2b(f.z); o.us[3] = f2b(f.w);
  *(unsigned long long*)(wbf + (size_t)idx * 4) = o.q;
}

// ---------------- per-WG Whh1 B-frag images -> global wimg1 ----------------
__global__ void k_repackImg1(const float* __restrict__ Whh1, unsigned short* wimg1) {
  size_t idx = (size_t)blockIdx.x * 256 + threadIdx.x;
  if (idx >= 4194304ull) return;
  int wg = (int)(idx >> 14);
  int r2 = (int)(idx & 16383);
  int ks = r2 >> 9;
  int l  = (r2 >> 3) & 63;
  int e  = r2 & 7;
  int nn = l & 15, kq = l >> 4;
  int row = (nn >> 2) * 1024 + wg * 4 + (nn & 3);
  int kk = ks * 32 + kq * 8 + e;
  wimg1[idx] = f2b(Whh1[(size_t)row * 1024 + kk]);
}

// ---------------- melpre[t][b][c] = ctx_pe . Wproj[c,1024:2048] + bproj[c] ----------------
__global__ __launch_bounds__(256) void k_melpre(const unsigned short* __restrict__ inp1c,
                                                const float* __restrict__ Wproj,
                                                const float* __restrict__ bproj,
                                                unsigned short* melpre, int t0, int tbeg) {
  extern __shared__ unsigned short ctx[];  // 32*1024 bf16
  int t = tbeg + blockIdx.x, tid = threadIdx.x;
  int tt = t - t0;
  for (int i = tid; i < 32768; i += 256)
    ctx[i] = inp1c[((size_t)tt * 32 + (i >> 10)) * 1280 + 256 + (i & 1023)];
  __syncthreads();
  if (tid < 240) {
    int c = tid % 80, bs = tid / 80;
    const float* w = Wproj + (size_t)c * 2048 + 1024;
    for (int b = bs; b < 32; b += 3) {
      float s = bproj[c];
      const unsigned short* x = ctx + b * 1024;
#pragma unroll 8
      for (int kk = 0; kk < 1024; ++kk) s += b2f(x[kk]) * w[kk];
      melpre[((size_t)t * 32 + b) * 80 + c] = f2b(s);
    }
  }
}

// 8 coherent 16B loads WITH drain
#define COH_LOAD8(d0,d1,d2,d3,d4,d5,d6,d7, p0,p1,p2,p3,p4,p5,p6,p7)       \
  asm volatile(                                                            \
    "global_load_dwordx4 %0, %8, off sc0 sc1\n\t"                          \
    "global_load_dwordx4 %1, %9, off sc0 sc1\n\t"                          \
    "global_load_dwordx4 %2, %10, off sc0 sc1\n\t"                         \
    "global_load_dwordx4 %3, %11, off sc0 sc1\n\t"                         \
    "global_load_dwordx4 %4, %12, off sc0 sc1\n\t"                         \
    "global_load_dwordx4 %5, %13, off sc0 sc1\n\t"                         \
    "global_load_dwordx4 %6, %14, off sc0 sc1\n\t"                         \
    "global_load_dwordx4 %7, %15, off sc0 sc1\n\t"                         \
    "s_waitcnt vmcnt(0)"                                                   \
    : "=&v"(d0), "=&v"(d1), "=&v"(d2), "=&v"(d3),                          \
      "=&v"(d4), "=&v"(d5), "=&v"(d6), "=&v"(d7)                           \
    : "v"(p0), "v"(p1), "v"(p2), "v"(p3),                                  \
      "v"(p4), "v"(p5), "v"(p6), "v"(p7)                                   \
    : "memory")

// 8 coherent 16B loads WITHOUT drain (issue-only)
#define COH_ISSUE8(d0,d1,d2,d3,d4,d5,d6,d7, p0,p1,p2,p3,p4,p5,p6,p7)      \
  asm volatile(                                                            \
    "global_load_dwordx4 %0, %8, off sc0 sc1\n\t"                          \
    "global_load_dwordx4 %1, %9, off sc0 sc1\n\t"                          \
    "global_load_dwordx4 %2, %10, off sc0 sc1\n\t"                         \
    "global_load_dwordx4 %3, %11, off sc0 sc1\n\t"                         \
    "global_load_dwordx4 %4, %12, off sc0 sc1\n\t"                         \
    "global_load_dwordx4 %5, %13, off sc0 sc1\n\t"                         \
    "global_load_dwordx4 %6, %14, off sc0 sc1\n\t"                         \
    "global_load_dwordx4 %7, %15, off sc0 sc1"                             \
    : "=&v"(d0), "=&v"(d1), "=&v"(d2), "=&v"(d3),                          \
      "=&v"(d4), "=&v"(d5), "=&v"(d6), "=&v"(d7)                           \
    : "v"(p0), "v"(p1), "v"(p2), "v"(p3),                                  \
      "v"(p4), "v"(p5), "v"(p6), "v"(p7)                                   \
    : "memory")

#define VM_DRAIN() asm volatile("s_waitcnt vmcnt(0)" ::: "memory")

// x-GEMM for step kn into xa0/xa1 (wid0-1; operands L2-cacheable)
#define XGEMM(kn)                                                                     \
  { xa0 = (f32x4){0.f,0.f,0.f,0.f}; xa1 = (f32x4){0.f,0.f,0.f,0.f};                   \
    int nn_ = lane & 15, kq_ = lane >> 4;                                             \
    int brow_ = wid * 16 + nn_;                                                       \
    int row_ = (nn_ >> 2) * 1024 + wg * 4 + (nn_ & 3);                                \
    size_t tt_ = (size_t)((kn) - k0 + 2);                                             \
    const unsigned short* arow_ = A.inp1c + (tt_ * 32 + brow_) * 1280 + kq_ * 8;      \
    const unsigned short* wrow_ = A.wbf + (size_t)row_ * 1280 + kq_ * 8;              \
    _Pragma("unroll 4")                                                               \
    for (int ks_ = 0; ks_ < 40; ks_ += 2) {                                           \
      bfrag8 aA_ = *(const bfrag8*)(arow_ + ks_ * 32);                                \
      bfrag8 aB_ = *(const bfrag8*)(arow_ + ks_ * 32 + 32);                           \
      bfrag8 b0_ = *(const bfrag8*)(wrow_ + ks_ * 32);                                \
      bfrag8 b1_ = *(const bfrag8*)(wrow_ + ks_ * 32 + 32);                           \
      xa0 = __builtin_amdgcn_mfma_f32_16x16x32_bf16(aA_, b0_, xa0, 0, 0, 0);          \
      xa1 = __builtin_amdgcn_mfma_f32_16x16x32_bf16(aB_, b1_, xa1, 0, 0, 0);          \
    } }

// consume 8 ulonglong2 (16 qwords = 8 ks-steps) against bp
#define MF8Q(base_ks, r0,r1,r2,r3,r4,r5,r6,r7)                                        \
  { const ulonglong2 rr_[8] = { r0,r1,r2,r3,r4,r5,r6,r7 };                            \
    _Pragma("unroll") for (int j_ = 0; j_ < 8; ++j_) {                                \
      union { unsigned long long q[2]; bfrag8 v; } u_;                                \
      u_.q[0] = rr_[j_].x; u_.q[1] = rr_[j_].y;                                       \
      f32x4* acc_ = ((base_ks + j_) & 1) ? &a1 : &a0;                                 \
      *acc_ = __builtin_amdgcn_mfma_f32_16x16x32_bf16(u_.v, bp[(base_ks + j_) * 64],  \
                                                      *acc_, 0, 0, 0); } }

// ---------------- persistent cooperative decoder ----------------
struct DecArgs {
  const unsigned short* inp1c;
  const unsigned short* wbf;
  const unsigned short* wimg1;
  const float* Wih2; const float* Whh2;
  const float* bih1; const float* bhh1; const float* bih2; const float* bhh2;
  const float* Wproj; const float* bproj;
  const unsigned short* melpre;
  unsigned short* h1; unsigned short* h2; float* cst;
  unsigned int* cnt; float* out_mel;
  int k0, k1;
};

// LDS (dynamic, 139264): img @0 (65536): Wih2 [0..2048), Whh2 [2048..4096)
//   h1s @65536 (65536) staged h1[k-1] XOR-swizzled
//   g1 @131072 (2176) | g2a @133248 | g2b @135424
//   c1 @137600 (512) | c2 @138112 (512) | bias1 @138624 | bias2 @138688
__global__ __launch_bounds__(512, 1) void k_decode(DecArgs A) {
  extern __shared__ char smem[];
  short* img       = (short*)smem;
  float (*g1)[17]  = (float(*)[17])(smem + 131072);
  float (*g2a)[17] = (float(*)[17])(smem + 133248);
  float (*g2b)[17] = (float(*)[17])(smem + 135424);
  float (*c1)[4]   = (float(*)[4])(smem + 137600);
  float (*c2)[4]   = (float(*)[4])(smem + 138112);
  float* bias1     = (float*)(smem + 138624);
  float* bias2     = (float*)(smem + 138688);

  int wg = blockIdx.x, tid = threadIdx.x;
  int wid = tid >> 6, lane = tid & 63;
  int k0 = A.k0, k1 = A.k1;

  // repack Wih2/Whh2 B-frag images into LDS
  for (int s = tid; s < 4096; s += 512) {
    int gi = s >> 11, r = s & 2047;
    int ks = r >> 6, l = r & 63;
    int nn = l & 15, kq = l >> 4;
    int row = (nn >> 2) * 1024 + wg * 4 + (nn & 3);
    const float* W = (gi == 0) ? A.Wih2 : A.Whh2;
    const float* src = W + (size_t)row * 1024 + ks * 32 + kq * 8;
    union { unsigned short us[8]; bfrag8 v; } t_;
#pragma unroll
    for (int e = 0; e < 8; ++e) t_.us[e] = f2b(src[e]);
    ((bfrag8*)img)[s] = t_.v;
  }
  if (tid < 16) {
    int row = (tid >> 2) * 1024 + wg * 4 + (tid & 3);
    bias1[tid] = A.bih1[row] + A.bhh1[row];
    bias2[tid] = A.bih2[row] + A.bhh2[row];
  }
  if (tid < 128) {
    int b = tid >> 2, jj = tid & 3;
    c1[b][jj] = (k0 == 0) ? 0.f : A.cst[((size_t)wg * 32 + b) * 4 + jj];
  } else if (tid < 256) {
    int b = (tid - 128) >> 2, jj = tid & 3;
    c2[b][jj] = (k0 == 0) ? 0.f : A.cst[32768 + ((size_t)wg * 32 + b) * 4 + jj];
  }
  __syncthreads();

  f32x4 xa0 = {0.f,0.f,0.f,0.f}, xa1 = {0.f,0.f,0.f,0.f};
  if (wid < 2 && k0 < 800) XGEMM(k0);

  long totspin = 0;
  for (int k = k0; k < k1; ++k) {
    bool do1 = (k < 800);
    bool do2 = (k >= 1 && k <= 800);

    // ---- stage h1[k-1] -> LDS (XOR-swizzled), single drain ----
    {
      const char* s1g = (const char*)(A.h1 + ((k - 1) & 1) * 32768);
      const char* p1 = s1g + tid * 16;
      ulonglong2 d0,d1,d2,d3,d4,d5,d6,d7;
      COH_LOAD8(d0,d1,d2,d3,d4,d5,d6,d7,
                p1, p1+8192, p1+16384, p1+24576, p1+32768, p1+40960, p1+49152, p1+57344);
#define STG_WR(j, va)                                                \
      { int m = (j)*512 + tid;                                       \
        int sw = (m * 16) ^ (((m >> 7) & 7) << 4);                   \
        *(ulonglong2*)(smem + 65536 + sw) = va; }
      STG_WR(0, d0); STG_WR(1, d1); STG_WR(2, d2); STG_WR(3, d3);
      STG_WR(4, d4); STG_WR(5, d5); STG_WR(6, d6); STG_WR(7, d7);
#undef STG_WR
    }
    __syncthreads();

    if (wid < 2) {
      if (do1) {
        int nn = lane & 15, kq = lane >> 4;
        int brow = wid * 16 + nn;
        f32x4 a0 = xa0, a1 = xa1;                      // x-GEMM from barrier shadow
        const bfrag8* bp = (const bfrag8*)(A.wimg1 + (size_t)wg * 16384) + lane;  // Whh1
        int sbase = 65536 + brow * 2048 + kq * 16;
        int sxor = (brow & 7) << 4;
#pragma unroll
        for (int ks = 0; ks < 32; ks += 2) {
          ulonglong2 v0 = *(const ulonglong2*)(smem + ((sbase + ks * 64) ^ sxor));
          ulonglong2 v1 = *(const ulonglong2*)(smem + ((sbase + (ks + 1) * 64) ^ sxor));
          union { unsigned long long q[2]; bfrag8 v; } aa, ab;
          aa.q[0] = v0.x; aa.q[1] = v0.y;
          ab.q[0] = v1.x; ab.q[1] = v1.y;
          a0 = __builtin_amdgcn_mfma_f32_16x16x32_bf16(aa.v, bp[ks * 64], a0, 0, 0, 0);
          a1 = __builtin_amdgcn_mfma_f32_16x16x32_bf16(ab.v, bp[(ks + 1) * 64], a1, 0, 0, 0);
        }
        f32x4 acc = a0 + a1;
#pragma unroll
        for (int q = 0; q < 4; ++q) g1[wid * 16 + kq * 4 + q][nn] = acc[q];
      }
    } else if (wid < 4) {
      if (do2) {                                        // LSTM2 h1-part from LDS, Wih2 LDS img
        int mt = wid - 2;
        int nn = lane & 15, kq = lane >> 4;
        int brow = mt * 16 + nn;
        f32x4 a0 = {0.f,0.f,0.f,0.f}, a1 = {0.f,0.f,0.f,0.f};
        const bfrag8* bp = (const bfrag8*)img + lane;
        int sbase = 65536 + brow * 2048 + kq * 16;
        int sxor = (brow & 7) << 4;
#pragma unroll
        for (int ks = 0; ks < 32; ks += 2) {
          ulonglong2 v0 = *(const ulonglong2*)(smem + ((sbase + ks * 64) ^ sxor));
          ulonglong2 v1 = *(const ulonglong2*)(smem + ((sbase + (ks + 1) * 64) ^ sxor));
          union { unsigned long long q[2]; bfrag8 v; } aa, ab;
          aa.q[0] = v0.x; aa.q[1] = v0.y;
          ab.q[0] = v1.x; ab.q[1] = v1.y;
          a0 = __builtin_amdgcn_mfma_f32_16x16x32_bf16(aa.v, bp[ks * 64], a0, 0, 0, 0);
          a1 = __builtin_amdgcn_mfma_f32_16x16x32_bf16(ab.v, bp[(ks + 1) * 64], a1, 0, 0, 0);
        }
        f32x4 acc = a0 + a1;
#pragma unroll
        for (int q = 0; q < 4; ++q) g2a[mt * 16 + kq * 4 + q][nn] = acc[q];
      }
    } else if (wid < 6) {
      if (do2) {                // LSTM2 h2-part: 32 coherent loads in flight, ONE drain
        int mt = wid - 4;
        int nn = lane & 15, kq = lane >> 4;
        int brow = mt * 16 + nn;
        f32x4 a0 = {0.f,0.f,0.f,0.f}, a1 = {0.f,0.f,0.f,0.f};
        const char* hp = (const char*)(A.h2 + (k & 1) * 32768) + brow * 2048 + kq * 16;
        const bfrag8* bp = (const bfrag8*)img + 2048 + lane;  // Whh2
        ulonglong2 r0,r1,r2,r3,r4,r5,r6,r7, s0,s1,s2,s3,s4,s5,s6,s7,
                   t0,t1,t2,t3,t4,t5,t6,t7, u0,u1,u2,u3,u4,u5,u6,u7;
        COH_ISSUE8(r0,r1,r2,r3,r4,r5,r6,r7,
                   hp+0*64, hp+1*64, hp+2*64, hp+3*64, hp+4*64, hp+5*64, hp+6*64, hp+7*64);
        COH_ISSUE8(s0,s1,s2,s3,s4,s5,s6,s7,
                   hp+8*64, hp+9*64, hp+10*64, hp+11*64, hp+12*64, hp+13*64, hp+14*64, hp+15*64);
        COH_ISSUE8(t0,t1,t2,t3,t4,t5,t6,t7,
                   hp+16*64, hp+17*64, hp+18*64, hp+19*64, hp+20*64, hp+21*64, hp+22*64, hp+23*64);
        COH_ISSUE8(u0,u1,u2,u3,u4,u5,u6,u7,
                   hp+24*64, hp+25*64, hp+26*64, hp+27*64, hp+28*64, hp+29*64, hp+30*64, hp+31*64);
        VM_DRAIN();
        MF8Q(0,  r0,r1,r2,r3,r4,r5,r6,r7);
        MF8Q(8,  s0,s1,s2,s3,s4,s5,s6,s7);
        MF8Q(16, t0,t1,t2,t3,t4,t5,t6,t7);
        MF8Q(24, u0,u1,u2,u3,u4,u5,u6,u7);
        f32x4 acc = a0 + a1;
#pragma unroll
        for (int q = 0; q < 4; ++q) g2b[mt * 16 + kq * 4 + q][nn] = acc[q];
      }
    } else {
      if (k >= 2 && wg < 80) {  // mel: 32 coherent loads in flight, ONE drain
        int t = k - 2;
        int L = (wid - 6) * 64 + lane;
        int b = L >> 2, q = L & 3;
        const char* hp = (const char*)(A.h2 + (k & 1) * 32768) + b * 2048 + q * 512;
        const float* wp = A.Wproj + (size_t)wg * 2048 + q * 256;
        ulonglong2 r0,r1,r2,r3,r4,r5,r6,r7, s0q,s1q,s2q,s3q,s4q,s5q,s6q,s7q,
                   t0q,t1q,t2q,t3q,t4q,t5q,t6q,t7q, u0q,u1q,u2q,u3q,u4q,u5q,u6q,u7q;
        COH_ISSUE8(r0,r1,r2,r3,r4,r5,r6,r7,
                   hp+0*16, hp+1*16, hp+2*16, hp+3*16, hp+4*16, hp+5*16, hp+6*16, hp+7*16);
        COH_ISSUE8(s0q,s1q,s2q,s3q,s4q,s5q,s6q,s7q,
                   hp+8*16, hp+9*16, hp+10*16, hp+11*16, hp+12*16, hp+13*16, hp+14*16, hp+15*16);
        COH_ISSUE8(t0q,t1q,t2q,t3q,t4q,t5q,t6q,t7q,
                   hp+16*16, hp+17*16, hp+18*16, hp+19*16, hp+20*16, hp+21*16, hp+22*16, hp+23*16);
        COH_ISSUE8(u0q,u1q,u2q,u3q,u4q,u5q,u6q,u7q,
                   hp+24*16, hp+25*16, hp+26*16, hp+27*16, hp+28*16, hp+29*16, hp+30*16, hp+31*16);
        VM_DRAIN();
        float s0 = 0.f, s1v = 0.f;
#define MELQ(ii, rv)                                                               \
        { union { unsigned long long q; unsigned short u[4]; } a_, b2_;            \
          a_.q = rv.x; b2_.q = rv.y;                                               \
          const float* w0_ = wp + (ii) * 8;                                        \
          s0  += b2f(a_.u[0])*w0_[0] + b2f(a_.u[1])*w0_[1] + b2f(a_.u[2])*w0_[2] + b2f(a_.u[3])*w0_[3]; \
          s1v += b2f(b2_.u[0])*w0_[4] + b2f(b2_.u[1])*w0_[5] + b2f(b2_.u[2])*w0_[6] + b2f(b2_.u[3])*w0_[7]; }
        MELQ(0,r0) MELQ(1,r1) MELQ(2,r2) MELQ(3,r3) MELQ(4,r4) MELQ(5,r5) MELQ(6,r6) MELQ(7,r7)
        MELQ(8,s0q) MELQ(9,s1q) MELQ(10,s2q) MELQ(11,s3q) MELQ(12,s4q) MELQ(13,s5q) MELQ(14,s6q) MELQ(15,s7q)
        MELQ(16,t0q) MELQ(17,t1q) MELQ(18,t2q) MELQ(19,t3q) MELQ(20,t4q) MELQ(21,t5q) MELQ(22,t6q) MELQ(23,t7q)
        MELQ(24,u0q) MELQ(25,u1q) MELQ(26,u2q) MELQ(27,u3q) MELQ(28,u4q) MELQ(29,u5q) MELQ(30,u6q) MELQ(31,u7q)
#undef MELQ
        float s = s0 + s1v;
        s += __shfl_xor(s, 1);
        s += __shfl_xor(s, 2);
        if (q == 0) {
          float add = b2f(A.melpre[((size_t)t * 32 + b) * 80 + wg]);
          A.out_mel[(size_t)b * 64000 + (size_t)wg * 800 + t] = s + add;   // fp32 output
        }
      }
    }
    __syncthreads();
    if (tid < 128) {
      if (do1) {
        int b = tid >> 2, jj = tid & 3;
        float gi = g1[b][jj]      + bias1[jj];
        float gf = g1[b][4 + jj]  + bias1[4 + jj];
        float gg = g1[b][8 + jj]  + bias1[8 + jj];
        float go = g1[b][12 + jj] + bias1[12 + jj];
        float c = c1[b][jj];
        float cn = sigf(gf) * c + sigf(gi) * tanhf(gg);
        c1[b][jj] = cn;
        float hn = sigf(go) * tanhf(cn);
        float ho = __shfl_xor(hn, 1);
        if ((jj & 1) == 0) {
          unsigned int pk = (unsigned int)f2b(hn) | ((unsigned int)f2b(ho) << 16);
          __hip_atomic_store((unsigned int*)(A.h1 + (k & 1) * 32768 + b * 1024 + wg * 4 + jj), pk,
                             __ATOMIC_RELAXED, AGENT);
        }
      }
    } else if (tid < 256) {
      if (do2) {
        int b = (tid - 128) >> 2, jj = tid & 3;
        float gi = g2a[b][jj]      + g2b[b][jj]      + bias2[jj];
        float gf = g2a[b][4 + jj]  + g2b[b][4 + jj]  + bias2[4 + jj];
        float gg = g2a[b][8 + jj]  + g2b[b][8 + jj]  + bias2[8 + jj];
        float go = g2a[b][12 + jj] + g2b[b][12 + jj] + bias2[12 + jj];
        float c = c2[b][jj];
        float cn = sigf(gf) * c + sigf(gi) * tanhf(gg);
        c2[b][jj] = cn;
        float hn = sigf(go) * tanhf(cn);
        float ho = __shfl_xor(hn, 1);
        if ((jj & 1) == 0) {
          unsigned int pk = (unsigned int)f2b(hn) | ((unsigned int)f2b(ho) << 16);
          __hip_atomic_store((unsigned int*)(A.h2 + ((k - 1) & 1) * 32768 + b * 1024 + wg * 4 + jj), pk,
                             __ATOMIC_RELAXED, AGENT);
        }
      }
    }
    __syncthreads();   // drains vmcnt(0): h-stores committed before arrive
    if (tid == 0) {
      asm volatile("s_waitcnt vmcnt(0)" ::: "memory");
      __hip_atomic_fetch_add(A.cnt + (wg & 15) * 16, 1u, __ATOMIC_RELAXED, AGENT);
    }
    // next step's x-GEMM in the barrier shadow (wid0-1; pollers are wid4 lanes 0-15)
    if (wid < 2) {
      int kn = k + 1;
      if (kn < k1 && kn < 800) XGEMM(kn);
    }
    if (tid >= 256 && tid < 272 && totspin >= 0) {
      int li = tid - 256;
      unsigned int tgt = (unsigned int)(k + 1) * 16u;
      while (__hip_atomic_load(A.cnt + li * 16, __ATOMIC_RELAXED, AGENT) < tgt) {
        __builtin_amdgcn_s_sleep(4);
        if (++totspin > (1l << 23)) {          // watchdog: record + free-run, never hang
          totspin = -1;
          __hip_atomic_fetch_add(A.cnt + 255, 1u, __ATOMIC_RELAXED, AGENT);
          break;
        }
      }
    }
    __syncthreads();
  }
  if (tid < 128) {
    int b = tid >> 2, jj = tid & 3;
    A.cst[((size_t)wg * 32 + b) * 4 + jj] = c1[b][jj];
  } else if (tid < 256) {
    int b = (tid - 128) >> 2, jj = tid & 3;
    A.cst[32768 + ((size_t)wg * 32 + b) * 4 + jj] = c2[b][jj];
  }
}

// ---------------- diagnostics (fp32) ----------------
__global__ void k_diag(float* out_mel, float wsmb) {
  out_mel[0] = 1000.f + wsmb;                 // ~1000+MB => ws too small
}
__global__ void k_verify(const unsigned int* cnt, float* out_mel) {
  unsigned int tot = 0;
  for (int i = 0; i < 16; ++i) tot += cnt[i * 16];
  if (tot != 802u * 256u)
    out_mel[0] = 3000.f + (float)tot * (1.f / 256.f);          // ~3000+ => decode stalled
}

extern "C" void kernel_launch(void* const* d_in, const int* in_sizes, int n_in,
                              void* d_out, int out_size, void* d_ws, size_t ws_size,
                              hipStream_t stream) {
  const float* memory = (const float*)d_in[0];
  const float* dur    = (const float*)d_in[1];
  const int*   dfi    = (const int*)d_in[2];
  const float* range  = (const float*)d_in[3];
  const float* din    = (const float*)d_in[4];
  const float* Wp1    = (const float*)d_in[6];
  const float* Wp2    = (const float*)d_in[7];
  const float* Wih1   = (const float*)d_in[8];
  const float* Whh1   = (const float*)d_in[9];
  const float* bih1   = (const float*)d_in[10];
  const float* bhh1   = (const float*)d_in[11];
  const float* Wih2   = (const float*)d_in[12];
  const float* Whh2   = (const float*)d_in[13];
  const float* bih2   = (const float*)d_in[14];
  const float* bhh2   = (const float*)d_in[15];
  const float* Wproj  = (const float*)d_in[16];
  const float* bproj  = (const float*)d_in[17];
  const float* u1     = (const float*)d_in[18];
  const float* u2     = (const float*)d_in[19];

  char* ws = (char*)d_ws;
  unsigned int* cnt   = (unsigned int*)ws;
  float* cvec         = (float*)(ws + 4096);
  float* coef         = cvec + 8192;
  float* inv2         = coef + 8192;
  float* pe           = (float*)(ws + 102400);
  unsigned short* h1  = (unsigned short*)(ws + 153600);
  unsigned short* h2  = h1 + 65536;
  float* cst          = (float*)(ws + 415744);
  unsigned short* melpre = (unsigned short*)(ws + 720896);
  unsigned short* wbf    = (unsigned short*)(ws + 4849664);
  unsigned short* wimg1  = (unsigned short*)(ws + 15728640);
  unsigned short* inp1c  = (unsigned short*)(ws + 41943040ull);

  float* out_mel   = (float*)d_out;                         // fp32 outputs (reference dtype)
  float* out_align = out_mel + 2048000;

  const size_t BASE = 41943040ull;
  int TC;
  if      (ws_size >= BASE + 802ull * 81920ull) TC = 800;
  else if (ws_size >= BASE + 202ull * 81920ull) TC = 200;
  else if (ws_size >= BASE +  82ull * 81920ull) TC = 80;
  else if (ws_size >= BASE +  42ull * 81920ull) TC = 40;
  else {
    k_diag<<<1, 1, 0, stream>>>(out_mel, (float)(ws_size >> 20));
    return;
  }

  hipFuncSetAttribute((const void*)k_decode, hipFuncAttributeMaxDynamicSharedMemorySize, 147456);
  hipFuncSetAttribute((const void*)k_melpre, hipFuncAttributeMaxDynamicSharedMemorySize, 98304);

  k_init<<<256, 256, 0, stream>>>((unsigned int*)(ws + 153600), cnt, pe);
  k_attn_prep<<<32, 256, 0, stream>>>(dur, range, cvec, coef, inv2);
  k_attn<<<dim3(800, 32), 256, 0, stream>>>(cvec, coef, inv2, out_align);
  k_repackW<<<5120, 256, 0, stream>>>(Wih1, wbf);
  k_repackImg1<<<16384, 256, 0, stream>>>(Whh1, wimg1);

  DecArgs da[20];
  int nch = (800 + TC - 1) / TC;
  for (int c = 0; c < nch; ++c) {
    int k0 = c * TC;
    int k1 = (c == nch - 1) ? 802 : (c + 1) * TC;
    int t0 = k0 - 2;
    int tbeg = t0 < 0 ? 0 : t0;
    int tend = k1 < 800 ? k1 : 800;
    int R = tend - tbeg;
    k_prenet<<<R, 256, 0, stream>>>(din, u1, u2, Wp1, Wp2, inp1c, t0, tbeg);
    k_ctx<<<dim3((R + 15) / 16, 32), 256, 0, stream>>>(cvec, coef, inv2, memory, inp1c, t0, tbeg, tend);
    k_pegather<<<(R * 4096 + 255) / 256, 256, 0, stream>>>(dfi, pe, inp1c, t0, tbeg, R);
    k_melpre<<<R, 256, 65536, stream>>>(inp1c, Wproj, bproj, melpre, t0, tbeg);

    da[c] = DecArgs{ inp1c, wbf, wimg1, Wih2, Whh2, bih1, bhh1, bih2, bhh2,
                     Wproj, bproj, melpre, h1, h2, cst, cnt, out_mel, k0, k1 };
    void* kp[1] = { &da[c] };
    hipLaunchCooperativeKernel((const void*)k_decode, dim3(256), dim3(512), kp, 139264, stream);
  }
  k_verify<<<1, 1, 0, stream>>>(cnt, out_mel);
}